// Round 2
// baseline (1581.072 us; speedup 1.0000x reference)
//
#include <hip/hip_runtime.h>

typedef float f32x4 __attribute__((ext_vector_type(4)));
typedef __bf16 bf16x8 __attribute__((ext_vector_type(8)));

__device__ __forceinline__ unsigned short f2bf(float f) {
  unsigned int u = __float_as_uint(f);
  u = (u + 0x7FFFu + ((u >> 16) & 1u)) >> 16;
  return (unsigned short)u;
}

__device__ __forceinline__ f32x4 mfma16(bf16x8 a, bf16x8 b, f32x4 c) {
  return __builtin_amdgcn_mfma_f32_16x16x32_bf16(a, b, c, 0, 0, 0);
}

// Stage 8 contiguous elements as bf16 into LDS (16B write).
__device__ __forceinline__ void load8_bf16(const unsigned short* p, unsigned short* d) {
  *(uint4*)d = *(const uint4*)p;
}
__device__ __forceinline__ void load8_bf16(const float* p, unsigned short* d) {
  float4 a = *(const float4*)p;
  float4 b = *(const float4*)(p + 4);
  __align__(16) unsigned short t[8] = {f2bf(a.x), f2bf(a.y), f2bf(a.z), f2bf(a.w),
                                       f2bf(b.x), f2bf(b.y), f2bf(b.z), f2bf(b.w)};
  *(uint4*)d = *(uint4*)t;
}

__device__ __forceinline__ void storeC(unsigned short* C, size_t idx, float v) { C[idx] = f2bf(v); }
__device__ __forceinline__ void storeC(float* C, size_t idx, float v) { C[idx] = v; }

// C[M,N] = A[M,K] * Bt[N,K]^T ; fp32 accum, bf16 MFMA compute.
// MODE 0: plain row-major store
// MODE 1: RoPE epilogue (q/k projection; rows are b*2048+s_raw, cols p_raw)
// MODE 2: RowLinear output-permutation store (N must be 1024, 2048 rows/batch)
template <int MODE, typename TA, typename TB, typename TC>
__global__ __launch_bounds__(256) void gemm_bt(const TA* __restrict__ A,
                                               const TB* __restrict__ Bt,
                                               TC* __restrict__ C,
                                               int M, int N, int K) {
  __shared__ __align__(16) unsigned short As[128][40];  // +8 pad: conflict-free b128 reads
  __shared__ __align__(16) unsigned short Bs[128][40];
  const int t = threadIdx.x;
  const int lane = t & 63;
  const int wid = t >> 6;
  const int quad = lane >> 4;
  const int l16 = lane & 15;
  const int wm = (wid >> 1) << 6;   // 2x2 wave grid, 64x64 per wave
  const int wn = (wid & 1) << 6;
  const int mbase = blockIdx.y * 128;
  const int nbase = blockIdx.x * 128;

  f32x4 acc[4][4] = {};

  for (int k0 = 0; k0 < K; k0 += 32) {
#pragma unroll
    for (int i = 0; i < 2; ++i) {
      int c = t + (i << 8);
      int row = c >> 2;
      int col = (c & 3) << 3;
      load8_bf16(A + (size_t)(mbase + row) * K + k0 + col, &As[row][col]);
      load8_bf16(Bt + (size_t)(nbase + row) * K + k0 + col, &Bs[row][col]);
    }
    __syncthreads();
    bf16x8 af[4], bfr[4];
#pragma unroll
    for (int mt = 0; mt < 4; ++mt)
      af[mt] = *(const bf16x8*)(&As[wm + mt * 16 + l16][quad * 8]);
#pragma unroll
    for (int nt = 0; nt < 4; ++nt)
      bfr[nt] = *(const bf16x8*)(&Bs[wn + nt * 16 + l16][quad * 8]);
#pragma unroll
    for (int mt = 0; mt < 4; ++mt)
#pragma unroll
      for (int nt = 0; nt < 4; ++nt)
        acc[mt][nt] = mfma16(af[mt], bfr[nt], acc[mt][nt]);
    __syncthreads();
  }

#pragma unroll
  for (int mt = 0; mt < 4; ++mt) {
#pragma unroll
    for (int nt = 0; nt < 4; ++nt) {
#pragma unroll
      for (int r = 0; r < 4; ++r) {
        int row_g = mbase + wm + mt * 16 + quad * 4 + r;  // C row = quad*4+reg (m89)
        int col_g = nbase + wn + nt * 16 + l16;           // C col = lane&15
        float v = acc[mt][nt][r];
        if (MODE == 1) {
          // interleaved RoPE; partner col = col^1 lives in lane^1
          float other = __shfl_xor(v, 1);
          int s = (((row_g & 2047) << 3) + (col_g >> 7)) & 2047;
          int d = col_g & 127;
          float invf = expf(-0.14391156f * (float)(d >> 1));  // ln(1e4)/64
          float ang = (float)s * invf;
          float cv = cosf(ang), sv = sinf(ang);
          v = (d & 1) ? (v * cv + other * sv) : (v * cv - other * sv);
          storeC(C, (size_t)row_g * N + col_g, v);
        } else if (MODE == 2) {
          int b = row_g >> 11;
          int g = ((row_g & 2047) << 10) + col_g;  // g = i*1024 + e
          int e2 = g >> 11;
          int s2 = g & 2047;
          storeC(C, (size_t)b * (2048 * 1024) + ((size_t)s2 << 10) + e2, v);
        } else {
          storeC(C, (size_t)row_g * N + col_g, v);
        }
      }
    }
  }
}

// Flash attention over [BH=32, S=2048, D=128]; BQ=128 (4 waves x 32 rows), BKV=64.
__global__ __launch_bounds__(256) void flash_attn(const unsigned short* __restrict__ Q,
                                                  const unsigned short* __restrict__ Kg,
                                                  const unsigned short* __restrict__ Vg,
                                                  unsigned short* __restrict__ O) {
  __shared__ __align__(16) unsigned short Ks[64][136];   // [kv][d] +8 pad
  __shared__ __align__(16) unsigned short Vt[128][72];   // [d][kv] +8 pad (transposed)
  __shared__ __align__(16) unsigned short Ps[4][32][72]; // per-wave P round-trip
  const int t = threadIdx.x;
  const int lane = t & 63;
  const int wid = t >> 6;
  const int quad = lane >> 4;
  const int l16 = lane & 15;
  const int bh = blockIdx.y;
  const int qbase = blockIdx.x * 128;
  const size_t base = (size_t)bh * (2048 * 128);

  // Q fragments, A-layout: m=lane&15, k=quad*8+j (+32 per ks)
  bf16x8 qf[2][4];
#pragma unroll
  for (int mt = 0; mt < 2; ++mt) {
    int row = qbase + wid * 32 + mt * 16 + l16;
#pragma unroll
    for (int ks = 0; ks < 4; ++ks)
      qf[mt][ks] = *(const bf16x8*)(Q + base + (size_t)row * 128 + ks * 32 + quad * 8);
  }

  f32x4 accO[2][8] = {};
  float mst[2][4], lst[2][4];
#pragma unroll
  for (int mt = 0; mt < 2; ++mt)
#pragma unroll
    for (int r = 0; r < 4; ++r) { mst[mt][r] = -__builtin_inff(); lst[mt][r] = 0.f; }

  for (int kv0 = 0; kv0 < 2048; kv0 += 64) {
    // stage K [64][128]
#pragma unroll
    for (int i = 0; i < 4; ++i) {
      int c = t + (i << 8);
      int row = c >> 4;
      int col = (c & 15) << 3;
      *(uint4*)(&Ks[row][col]) = *(const uint4*)(Kg + base + (size_t)(kv0 + row) * 128 + col);
    }
    // stage V transposed [d][kv]; lane-staggered scalar writes (bank-conflict fix)
#pragma unroll
    for (int i = 0; i < 4; ++i) {
      int c = t + (i << 8);
      int row = c >> 4;
      int col = (c & 15) << 3;
      __align__(16) unsigned short tmp[8];
      *(uint4*)tmp = *(const uint4*)(Vg + base + (size_t)(kv0 + row) * 128 + col);
#pragma unroll
      for (int j = 0; j < 8; ++j) {
        int jj = (j + lane) & 7;
        Vt[col + jj][row] = tmp[jj];
      }
    }
    __syncthreads();

    // S = Q K^T * scale
    f32x4 accS[2][4] = {};
#pragma unroll
    for (int nt = 0; nt < 4; ++nt) {
      bf16x8 kf[4];
#pragma unroll
      for (int ks = 0; ks < 4; ++ks)
        kf[ks] = *(const bf16x8*)(&Ks[nt * 16 + l16][ks * 32 + quad * 8]);
#pragma unroll
      for (int mt = 0; mt < 2; ++mt)
#pragma unroll
        for (int ks = 0; ks < 4; ++ks)
          accS[mt][nt] = mfma16(qf[mt][ks], kf[ks], accS[mt][nt]);
    }
    const float scale = 0.3535533905932738f;  // 1/sqrt(H=8), faithful to source
#pragma unroll
    for (int mt = 0; mt < 2; ++mt)
#pragma unroll
      for (int nt = 0; nt < 4; ++nt)
        accS[mt][nt] *= scale;

    // online softmax; row r of a 16-tile lives in the 16 lanes of one quad group
#pragma unroll
    for (int mt = 0; mt < 2; ++mt) {
#pragma unroll
      for (int r = 0; r < 4; ++r) {
        float mx = fmaxf(fmaxf(accS[mt][0][r], accS[mt][1][r]),
                         fmaxf(accS[mt][2][r], accS[mt][3][r]));
#pragma unroll
        for (int off = 1; off < 16; off <<= 1) mx = fmaxf(mx, __shfl_xor(mx, off));
        float mnew = fmaxf(mst[mt][r], mx);
        float alpha = expf(mst[mt][r] - mnew);
        float psum = 0.f;
#pragma unroll
        for (int nt = 0; nt < 4; ++nt) {
          float p = expf(accS[mt][nt][r] - mnew);
          accS[mt][nt][r] = p;
          psum += p;
        }
#pragma unroll
        for (int off = 1; off < 16; off <<= 1) psum += __shfl_xor(psum, off);
        lst[mt][r] = lst[mt][r] * alpha + psum;
        mst[mt][r] = mnew;
#pragma unroll
        for (int dt = 0; dt < 8; ++dt) accO[mt][dt][r] *= alpha;
      }
    }

    // P: C-layout -> bf16 -> LDS -> A-layout (m120 pattern)
#pragma unroll
    for (int mt = 0; mt < 2; ++mt)
#pragma unroll
      for (int nt = 0; nt < 4; ++nt)
#pragma unroll
        for (int r = 0; r < 4; ++r)
          Ps[wid][mt * 16 + quad * 4 + r][nt * 16 + l16] = f2bf(accS[mt][nt][r]);
    __syncthreads();

    bf16x8 pf[2][2];
#pragma unroll
    for (int mt = 0; mt < 2; ++mt)
#pragma unroll
      for (int ks = 0; ks < 2; ++ks)
        pf[mt][ks] = *(const bf16x8*)(&Ps[wid][mt * 16 + l16][ks * 32 + quad * 8]);
#pragma unroll
    for (int dt = 0; dt < 8; ++dt) {
      bf16x8 vf[2];
#pragma unroll
      for (int ks = 0; ks < 2; ++ks)
        vf[ks] = *(const bf16x8*)(&Vt[dt * 16 + l16][ks * 32 + quad * 8]);
#pragma unroll
      for (int mt = 0; mt < 2; ++mt)
#pragma unroll
        for (int ks = 0; ks < 2; ++ks)
          accO[mt][dt] = mfma16(pf[mt][ks], vf[ks], accO[mt][dt]);
    }
    __syncthreads();
  }

#pragma unroll
  for (int mt = 0; mt < 2; ++mt) {
#pragma unroll
    for (int r = 0; r < 4; ++r) {
      float inv = 1.f / lst[mt][r];
      int row = qbase + wid * 32 + mt * 16 + quad * 4 + r;
#pragma unroll
      for (int dt = 0; dt < 8; ++dt) {
        int col = dt * 16 + l16;
        O[base + (size_t)row * 128 + col] = f2bf(accO[mt][dt][r] * inv);
      }
    }
  }
}

// o4[b,h,s,d] -> x2 rows i=h*256+d*2+(s>>10), cols j=s&1023 (RowLinear pre-shuffle)
__global__ __launch_bounds__(256) void transpose_o(const unsigned short* __restrict__ O4,
                                                   unsigned short* __restrict__ X2) {
  __shared__ __align__(16) unsigned short tile[64][72];
  const int t = threadIdx.x;
  const int s0 = blockIdx.x * 64;
  const int d0 = blockIdx.y * 64;
  const int bh = blockIdx.z;
  const int b = bh >> 3;
  const int h = bh & 7;
  const size_t src = (size_t)bh * (2048 * 128);
#pragma unroll
  for (int i = 0; i < 2; ++i) {
    int c = t + (i << 8);
    int sr = c >> 3;
    int dc = (c & 7) << 3;
    *(uint4*)(&tile[sr][dc]) = *(const uint4*)(O4 + src + (size_t)(s0 + sr) * 128 + d0 + dc);
  }
  __syncthreads();
#pragma unroll
  for (int i = 0; i < 2; ++i) {
    int c = t + (i << 8);
    int dr = c >> 3;
    int sc = (c & 7) << 3;
    __align__(16) unsigned short tmp[8];
#pragma unroll
    for (int j = 0; j < 8; ++j) tmp[j] = tile[sc + j][dr];
    int d = d0 + dr;
    int srow = s0 + sc;
    size_t dst = (size_t)b * (2048 * 1024) +
                 (size_t)(h * 256 + d * 2 + (srow >> 10)) * 1024 + (srow & 1023);
    *(uint4*)(&X2[dst]) = *(uint4*)tmp;
  }
}

extern "C" void kernel_launch(void* const* d_in, const int* in_sizes, int n_in,
                              void* d_out, int out_size, void* d_ws, size_t ws_size,
                              hipStream_t stream) {
  const float* emb = (const float*)d_in[0];
  const float* W1  = (const float*)d_in[1];
  const float* W2  = (const float*)d_in[2];
  const float* W3  = (const float*)d_in[3];
  const float* Wo  = (const float*)d_in[4];
  float* out = (float*)d_out;

  const size_t NELEM = (size_t)8 * 1024 * 1024;  // 8388608 bf16 per [B*S, P] buffer
  unsigned short* q  = (unsigned short*)d_ws;
  unsigned short* k  = q + NELEM;
  unsigned short* v  = k + NELEM;
  unsigned short* o4 = v + NELEM;
  unsigned short* x2 = q;  // q dead after flash_attn; reuse

  dim3 blk(256, 1, 1);
  dim3 gp(8, 64, 1);  // (N/128, M/128)
  gemm_bt<1><<<gp, blk, 0, stream>>>(emb, W1, q, 8192, 1024, 1024);
  gemm_bt<1><<<gp, blk, 0, stream>>>(emb, W2, k, 8192, 1024, 1024);
  gemm_bt<0><<<gp, blk, 0, stream>>>(emb, W3, v, 8192, 1024, 1024);
  flash_attn<<<dim3(16, 32, 1), blk, 0, stream>>>(q, k, v, o4);
  transpose_o<<<dim3(32, 2, 32), blk, 0, stream>>>(o4, x2);
  gemm_bt<2><<<gp, blk, 0, stream>>>(x2, Wo, out, 8192, 1024, 1024);
}

// Round 3
// 566.397 us; speedup vs baseline: 2.7915x; 2.7915x over previous
//
#include <hip/hip_runtime.h>

typedef float f32x4 __attribute__((ext_vector_type(4)));
typedef __bf16 bf16x8 __attribute__((ext_vector_type(8)));

__device__ __forceinline__ unsigned short f2bf(float f) {
  unsigned int u = __float_as_uint(f);
  u = (u + 0x7FFFu + ((u >> 16) & 1u)) >> 16;
  return (unsigned short)u;
}

__device__ __forceinline__ f32x4 mfma16(bf16x8 a, bf16x8 b, f32x4 c) {
  return __builtin_amdgcn_mfma_f32_16x16x32_bf16(a, b, c, 0, 0, 0);
}

// Stage 8 contiguous elements as bf16 into LDS (16B write).
__device__ __forceinline__ void load8_bf16(const unsigned short* p, unsigned short* d) {
  *(uint4*)d = *(const uint4*)p;
}
__device__ __forceinline__ void load8_bf16(const float* p, unsigned short* d) {
  float4 a = *(const float4*)p;
  float4 b = *(const float4*)(p + 4);
  __align__(16) unsigned short t[8] = {f2bf(a.x), f2bf(a.y), f2bf(a.z), f2bf(a.w),
                                       f2bf(b.x), f2bf(b.y), f2bf(b.z), f2bf(b.w)};
  *(uint4*)d = *(uint4*)t;
}

__device__ __forceinline__ void storeC(unsigned short* C, size_t idx, float v) { C[idx] = f2bf(v); }
__device__ __forceinline__ void storeC(float* C, size_t idx, float v) { C[idx] = v; }

// C[M,N] = A[M,K] * Bt[N,K]^T ; fp32 accum, bf16 MFMA compute.
// MODE 0: plain row-major store (bf16)
// MODE 1: RoPE epilogue (q/k projection; rows are b*2048+s_raw, cols p_raw) (bf16)
// MODE 2: RowLinear output-permutation, LDS-transposed coalesced fp32 store
template <int MODE, typename TA, typename TB, typename TC>
__global__ __launch_bounds__(256) void gemm_bt(const TA* __restrict__ A,
                                               const TB* __restrict__ Bt,
                                               TC* __restrict__ C,
                                               int M, int N, int K) {
  constexpr int SMEM_BYTES = (MODE == 2) ? (128 * 68 * 4) : (2 * 128 * 40 * 2);
  __shared__ __align__(16) char smem_raw[SMEM_BYTES];
  auto As = (unsigned short(*)[40])smem_raw;                    // 128x40 bf16 (+8 pad)
  auto Bs = (unsigned short(*)[40])(smem_raw + 128 * 40 * 2);
  const int t = threadIdx.x;
  const int lane = t & 63;
  const int wid = t >> 6;
  const int quad = lane >> 4;
  const int l16 = lane & 15;
  const int wm = (wid >> 1) << 6;   // 2x2 wave grid, 64x64 per wave
  const int wn = (wid & 1) << 6;
  const int mbase = blockIdx.y * 128;
  const int nbase = blockIdx.x * 128;

  f32x4 acc[4][4] = {};

  for (int k0 = 0; k0 < K; k0 += 32) {
#pragma unroll
    for (int i = 0; i < 2; ++i) {
      int c = t + (i << 8);
      int row = c >> 2;
      int col = (c & 3) << 3;
      load8_bf16(A + (size_t)(mbase + row) * K + k0 + col, &As[row][col]);
      load8_bf16(Bt + (size_t)(nbase + row) * K + k0 + col, &Bs[row][col]);
    }
    __syncthreads();
    bf16x8 af[4], bfr[4];
#pragma unroll
    for (int mt = 0; mt < 4; ++mt)
      af[mt] = *(const bf16x8*)(&As[wm + mt * 16 + l16][quad * 8]);
#pragma unroll
    for (int nt = 0; nt < 4; ++nt)
      bfr[nt] = *(const bf16x8*)(&Bs[wn + nt * 16 + l16][quad * 8]);
#pragma unroll
    for (int mt = 0; mt < 4; ++mt)
#pragma unroll
      for (int nt = 0; nt < 4; ++nt)
        acc[mt][nt] = mfma16(af[mt], bfr[nt], acc[mt][nt]);
    __syncthreads();
  }

  if constexpr (MODE == 2) {
    // out[b][s2][e2], s2 = (row&1)*1024 + col, e2 = (row&2047)>>1.
    // Pass p handles acc rows with r&1 == p (row parity == r parity here).
    float(*Ts)[68] = (float(*)[68])smem_raw;  // [col_local 128][e_local 64] +4 pad
    const int b = mbase >> 11;
    const int ebase = (mbase & 2047) >> 1;
#pragma unroll
    for (int p = 0; p < 2; ++p) {
      __syncthreads();
#pragma unroll
      for (int mt = 0; mt < 4; ++mt)
#pragma unroll
        for (int nt = 0; nt < 4; ++nt)
#pragma unroll
          for (int rr = p; rr < 4; rr += 2) {
            int col_local = wn + nt * 16 + l16;
            int row_local = wm + mt * 16 + quad * 4 + rr;
            Ts[col_local][row_local >> 1] = acc[mt][nt][rr];
          }
      __syncthreads();
      int srow = t >> 1;         // 128 output rows in this pass
      int e0 = (t & 1) << 5;     // half of 64 e-columns
      float* dst = (float*)C + (size_t)b * 2097152 +
                   (size_t)(p * 1024 + nbase + srow) * 1024 + ebase + e0;
#pragma unroll
      for (int j = 0; j < 8; ++j)
        ((float4*)dst)[j] = *(const float4*)&Ts[srow][e0 + j * 4];
    }
    return;
  }

#pragma unroll
  for (int mt = 0; mt < 4; ++mt) {
#pragma unroll
    for (int nt = 0; nt < 4; ++nt) {
#pragma unroll
      for (int r = 0; r < 4; ++r) {
        int row_g = mbase + wm + mt * 16 + quad * 4 + r;  // C row = quad*4+reg (m89)
        int col_g = nbase + wn + nt * 16 + l16;           // C col = lane&15
        float v = acc[mt][nt][r];
        if (MODE == 1) {
          // interleaved RoPE; partner col = col^1 lives in lane^1
          float other = __shfl_xor(v, 1);
          int s = (((row_g & 2047) << 3) + (col_g >> 7)) & 2047;
          int d = col_g & 127;
          float invf = __expf(-0.14391156f * (float)(d >> 1));  // ln(1e4)/64
          float ang = (float)s * invf;
          float sv, cv;
          __sincosf(ang, &sv, &cv);
          v = (d & 1) ? (v * cv + other * sv) : (v * cv - other * sv);
          storeC(C, (size_t)row_g * N + col_g, v);
        } else {
          storeC(C, (size_t)row_g * N + col_g, v);
        }
      }
    }
  }
}

// Flash attention over [BH=32, S=2048, D=128]; BQ=64 (4 waves x 16 rows), BKV=64.
__global__ __launch_bounds__(256) void flash_attn(const unsigned short* __restrict__ Q,
                                                  const unsigned short* __restrict__ Kg,
                                                  const unsigned short* __restrict__ Vg,
                                                  unsigned short* __restrict__ O) {
  __shared__ __align__(16) unsigned short Ks[64][136];   // [kv][d] +8 pad
  __shared__ __align__(16) unsigned short Vt[128][72];   // [d][kv] +8 pad (transposed)
  __shared__ __align__(16) unsigned short Ps[4][16][72]; // per-wave P round-trip
  const int t = threadIdx.x;
  const int lane = t & 63;
  const int wid = t >> 6;
  const int quad = lane >> 4;
  const int l16 = lane & 15;
  const int bh = blockIdx.y;
  const int qbase = blockIdx.x * 64;
  const size_t base = (size_t)bh * (2048 * 128);

  // Q fragments, A-layout: m=lane&15, k=quad*8+j (+32 per ks)
  bf16x8 qf[4];
  {
    int row = qbase + wid * 16 + l16;
#pragma unroll
    for (int ks = 0; ks < 4; ++ks)
      qf[ks] = *(const bf16x8*)(Q + base + (size_t)row * 128 + ks * 32 + quad * 8);
  }

  f32x4 accO[8] = {};
  float mst[4], lst[4];
#pragma unroll
  for (int r = 0; r < 4; ++r) { mst[r] = -__builtin_inff(); lst[r] = 0.f; }

  for (int kv0 = 0; kv0 < 2048; kv0 += 64) {
    // stage K [64][128]
#pragma unroll
    for (int i = 0; i < 4; ++i) {
      int c = t + (i << 8);
      int row = c >> 4;
      int col = (c & 15) << 3;
      *(uint4*)(&Ks[row][col]) = *(const uint4*)(Kg + base + (size_t)(kv0 + row) * 128 + col);
    }
    // stage V transposed [d][kv]; lane-staggered scalar writes
#pragma unroll
    for (int i = 0; i < 4; ++i) {
      int c = t + (i << 8);
      int row = c >> 4;
      int col = (c & 15) << 3;
      __align__(16) unsigned short tmp[8];
      *(uint4*)tmp = *(const uint4*)(Vg + base + (size_t)(kv0 + row) * 128 + col);
#pragma unroll
      for (int j = 0; j < 8; ++j) {
        int jj = (j + lane) & 7;
        Vt[col + jj][row] = tmp[jj];
      }
    }
    __syncthreads();

    // S = Q K^T * scale
    f32x4 accS[4] = {};
#pragma unroll
    for (int nt = 0; nt < 4; ++nt) {
      bf16x8 kf[4];
#pragma unroll
      for (int ks = 0; ks < 4; ++ks)
        kf[ks] = *(const bf16x8*)(&Ks[nt * 16 + l16][ks * 32 + quad * 8]);
#pragma unroll
      for (int ks = 0; ks < 4; ++ks)
        accS[nt] = mfma16(qf[ks], kf[ks], accS[nt]);
    }
    const float scale = 0.3535533905932738f;  // 1/sqrt(H=8), faithful to source
#pragma unroll
    for (int nt = 0; nt < 4; ++nt) accS[nt] *= scale;

    // online softmax; row r spans the 16 lanes of one quad group
#pragma unroll
    for (int r = 0; r < 4; ++r) {
      float mx = fmaxf(fmaxf(accS[0][r], accS[1][r]), fmaxf(accS[2][r], accS[3][r]));
#pragma unroll
      for (int off = 1; off < 16; off <<= 1) mx = fmaxf(mx, __shfl_xor(mx, off));
      float mnew = fmaxf(mst[r], mx);
      float alpha = __expf(mst[r] - mnew);
      float psum = 0.f;
#pragma unroll
      for (int nt = 0; nt < 4; ++nt) {
        float p = __expf(accS[nt][r] - mnew);
        accS[nt][r] = p;
        psum += p;
      }
#pragma unroll
      for (int off = 1; off < 16; off <<= 1) psum += __shfl_xor(psum, off);
      lst[r] = lst[r] * alpha + psum;
      mst[r] = mnew;
#pragma unroll
      for (int dt = 0; dt < 8; ++dt) accO[dt][r] *= alpha;
    }

    // P: C-layout -> bf16 -> LDS -> A-layout. Wave-local: DS ops are in-order
    // within a wave, so no barrier needed between write and read.
#pragma unroll
    for (int nt = 0; nt < 4; ++nt)
#pragma unroll
      for (int r = 0; r < 4; ++r)
        Ps[wid][quad * 4 + r][nt * 16 + l16] = f2bf(accS[nt][r]);

    bf16x8 pf[2];
#pragma unroll
    for (int ks = 0; ks < 2; ++ks)
      pf[ks] = *(const bf16x8*)(&Ps[wid][l16][ks * 32 + quad * 8]);
#pragma unroll
    for (int dt = 0; dt < 8; ++dt) {
      bf16x8 vf[2];
#pragma unroll
      for (int ks = 0; ks < 2; ++ks)
        vf[ks] = *(const bf16x8*)(&Vt[dt * 16 + l16][ks * 32 + quad * 8]);
#pragma unroll
      for (int ks = 0; ks < 2; ++ks)
        accO[dt] = mfma16(pf[ks], vf[ks], accO[dt]);
    }
    __syncthreads();  // guard Ks/Vt restage of next iteration
  }

#pragma unroll
  for (int r = 0; r < 4; ++r) {
    float inv = 1.f / lst[r];
    int row = qbase + wid * 16 + quad * 4 + r;
#pragma unroll
    for (int dt = 0; dt < 8; ++dt) {
      int col = dt * 16 + l16;
      O[base + (size_t)row * 128 + col] = f2bf(accO[dt][r] * inv);
    }
  }
}

// o4[b,h,s,d] -> x2 rows i=h*256+d*2+(s>>10), cols j=s&1023 (RowLinear pre-shuffle)
__global__ __launch_bounds__(256) void transpose_o(const unsigned short* __restrict__ O4,
                                                   unsigned short* __restrict__ X2) {
  __shared__ __align__(16) unsigned short tile[64][72];
  const int t = threadIdx.x;
  const int s0 = blockIdx.x * 64;
  const int d0 = blockIdx.y * 64;
  const int bh = blockIdx.z;
  const int b = bh >> 3;
  const int h = bh & 7;
  const size_t src = (size_t)bh * (2048 * 128);
#pragma unroll
  for (int i = 0; i < 2; ++i) {
    int c = t + (i << 8);
    int sr = c >> 3;
    int dc = (c & 7) << 3;
    *(uint4*)(&tile[sr][dc]) = *(const uint4*)(O4 + src + (size_t)(s0 + sr) * 128 + d0 + dc);
  }
  __syncthreads();
#pragma unroll
  for (int i = 0; i < 2; ++i) {
    int c = t + (i << 8);
    int dr = c >> 3;
    int sc = (c & 7) << 3;
    __align__(16) unsigned short tmp[8];
#pragma unroll
    for (int j = 0; j < 8; ++j) tmp[j] = tile[sc + j][dr];
    int d = d0 + dr;
    int srow = s0 + sc;
    size_t dst = (size_t)b * (2048 * 1024) +
                 (size_t)(h * 256 + d * 2 + (srow >> 10)) * 1024 + (srow & 1023);
    *(uint4*)(&X2[dst]) = *(uint4*)tmp;
  }
}

extern "C" void kernel_launch(void* const* d_in, const int* in_sizes, int n_in,
                              void* d_out, int out_size, void* d_ws, size_t ws_size,
                              hipStream_t stream) {
  const float* emb = (const float*)d_in[0];
  const float* W1  = (const float*)d_in[1];
  const float* W2  = (const float*)d_in[2];
  const float* W3  = (const float*)d_in[3];
  const float* Wo  = (const float*)d_in[4];
  float* out = (float*)d_out;

  const size_t NELEM = (size_t)8 * 1024 * 1024;  // 8388608 bf16 per [B*S, P] buffer
  unsigned short* q  = (unsigned short*)d_ws;
  unsigned short* k  = q + NELEM;
  unsigned short* v  = k + NELEM;
  unsigned short* o4 = v + NELEM;
  unsigned short* x2 = q;  // q dead after flash_attn; reuse

  dim3 blk(256, 1, 1);
  dim3 gp(8, 64, 1);  // (N/128, M/128)
  gemm_bt<1><<<gp, blk, 0, stream>>>(emb, W1, q, 8192, 1024, 1024);
  gemm_bt<1><<<gp, blk, 0, stream>>>(emb, W2, k, 8192, 1024, 1024);
  gemm_bt<0><<<gp, blk, 0, stream>>>(emb, W3, v, 8192, 1024, 1024);
  flash_attn<<<dim3(32, 32, 1), blk, 0, stream>>>(q, k, v, o4);
  transpose_o<<<dim3(32, 2, 32), blk, 0, stream>>>(o4, x2);
  gemm_bt<2><<<gp, blk, 0, stream>>>(x2, Wo, out, 8192, 1024, 1024);
}

// Round 4
// 530.805 us; speedup vs baseline: 2.9786x; 1.0671x over previous
//
#include <hip/hip_runtime.h>

typedef float f32x4 __attribute__((ext_vector_type(4)));
typedef __bf16 bf16x8 __attribute__((ext_vector_type(8)));

__device__ __forceinline__ unsigned short f2bf(float f) {
  unsigned int u = __float_as_uint(f);
  u = (u + 0x7FFFu + ((u >> 16) & 1u)) >> 16;
  return (unsigned short)u;
}

__device__ __forceinline__ f32x4 mfma16(bf16x8 a, bf16x8 b, f32x4 c) {
  return __builtin_amdgcn_mfma_f32_16x16x32_bf16(a, b, c, 0, 0, 0);
}

// Stage 8 contiguous elements as bf16 into LDS (16B write).
__device__ __forceinline__ void load8_bf16(const unsigned short* p, unsigned short* d) {
  *(uint4*)d = *(const uint4*)p;
}
__device__ __forceinline__ void load8_bf16(const float* p, unsigned short* d) {
  float4 a = *(const float4*)p;
  float4 b = *(const float4*)(p + 4);
  __align__(16) unsigned short t[8] = {f2bf(a.x), f2bf(a.y), f2bf(a.z), f2bf(a.w),
                                       f2bf(b.x), f2bf(b.y), f2bf(b.z), f2bf(b.w)};
  *(uint4*)d = *(uint4*)t;
}

__device__ __forceinline__ void storeC(unsigned short* C, size_t idx, float v) { C[idx] = f2bf(v); }
__device__ __forceinline__ void storeC(float* C, size_t idx, float v) { C[idx] = v; }

// Fused QKV projection: C_sel[8192,1024] = emb[8192,1024] x Wsel^T, RoPE on q,k.
// blockIdx.x in [0,24): sel = x>>3 (0:q/W1, 1:k/W2, 2:v/W3), nb = (x&7)*128.
__global__ __launch_bounds__(256) void gemm_qkv(const float* __restrict__ A,
                                                const float* __restrict__ W1,
                                                const float* __restrict__ W2,
                                                const float* __restrict__ W3,
                                                unsigned short* __restrict__ q,
                                                unsigned short* __restrict__ k,
                                                unsigned short* __restrict__ v) {
  __shared__ __align__(16) unsigned short As[128][40];
  __shared__ __align__(16) unsigned short Bs[128][40];
  const int t = threadIdx.x;
  const int lane = t & 63;
  const int wid = t >> 6;
  const int quad = lane >> 4;
  const int l16 = lane & 15;
  const int wm = (wid >> 1) << 6;
  const int wn = (wid & 1) << 6;
  const int sel = blockIdx.x >> 3;
  const int nb = (blockIdx.x & 7) << 7;
  const int mbase = blockIdx.y * 128;
  const float* Bt = (sel == 0) ? W1 : (sel == 1) ? W2 : W3;
  unsigned short* C = (sel == 0) ? q : (sel == 1) ? k : v;

  f32x4 acc[4][4] = {};

  for (int k0 = 0; k0 < 1024; k0 += 32) {
#pragma unroll
    for (int i = 0; i < 2; ++i) {
      int c = t + (i << 8);
      int row = c >> 2;
      int col = (c & 3) << 3;
      load8_bf16(A + (size_t)(mbase + row) * 1024 + k0 + col, &As[row][col]);
      load8_bf16(Bt + (size_t)(nb + row) * 1024 + k0 + col, &Bs[row][col]);
    }
    __syncthreads();
    bf16x8 af[4], bfr[4];
#pragma unroll
    for (int mt = 0; mt < 4; ++mt)
      af[mt] = *(const bf16x8*)(&As[wm + mt * 16 + l16][quad * 8]);
#pragma unroll
    for (int nt = 0; nt < 4; ++nt)
      bfr[nt] = *(const bf16x8*)(&Bs[wn + nt * 16 + l16][quad * 8]);
#pragma unroll
    for (int mt = 0; mt < 4; ++mt)
#pragma unroll
      for (int nt = 0; nt < 4; ++nt)
        acc[mt][nt] = mfma16(af[mt], bfr[nt], acc[mt][nt]);
    __syncthreads();
  }

  const bool rope = (sel < 2);
#pragma unroll
  for (int mt = 0; mt < 4; ++mt) {
#pragma unroll
    for (int nt = 0; nt < 4; ++nt) {
#pragma unroll
      for (int r = 0; r < 4; ++r) {
        int row_g = mbase + wm + mt * 16 + quad * 4 + r;
        int col_g = nb + wn + nt * 16 + l16;
        float val = acc[mt][nt][r];
        if (rope) {
          float other = __shfl_xor(val, 1);
          int s = (((row_g & 2047) << 3) + (col_g >> 7)) & 2047;
          int d = col_g & 127;
          float invf = __expf(-0.14391156f * (float)(d >> 1));  // ln(1e4)/64
          float ang = (float)s * invf;
          float sv, cv;
          __sincosf(ang, &sv, &cv);
          val = (d & 1) ? (val * cv + other * sv) : (val * cv - other * sv);
        }
        C[(size_t)row_g * 1024 + col_g] = f2bf(val);
      }
    }
  }
}

// Final projection with RowLinear output-permutation, coalesced fp32 store.
__global__ __launch_bounds__(256) void gemm_out(const unsigned short* __restrict__ A,
                                                const float* __restrict__ Bt,
                                                float* __restrict__ C) {
  __shared__ __align__(16) char smem_raw[128 * 68 * 4];
  auto As = (unsigned short(*)[40])smem_raw;
  auto Bs = (unsigned short(*)[40])(smem_raw + 128 * 40 * 2);
  const int t = threadIdx.x;
  const int lane = t & 63;
  const int wid = t >> 6;
  const int quad = lane >> 4;
  const int l16 = lane & 15;
  const int wm = (wid >> 1) << 6;
  const int wn = (wid & 1) << 6;
  const int mbase = blockIdx.y * 128;
  const int nbase = blockIdx.x * 128;

  f32x4 acc[4][4] = {};

  for (int k0 = 0; k0 < 1024; k0 += 32) {
#pragma unroll
    for (int i = 0; i < 2; ++i) {
      int c = t + (i << 8);
      int row = c >> 2;
      int col = (c & 3) << 3;
      load8_bf16(A + (size_t)(mbase + row) * 1024 + k0 + col, &As[row][col]);
      load8_bf16(Bt + (size_t)(nbase + row) * 1024 + k0 + col, &Bs[row][col]);
    }
    __syncthreads();
    bf16x8 af[4], bfr[4];
#pragma unroll
    for (int mt = 0; mt < 4; ++mt)
      af[mt] = *(const bf16x8*)(&As[wm + mt * 16 + l16][quad * 8]);
#pragma unroll
    for (int nt = 0; nt < 4; ++nt)
      bfr[nt] = *(const bf16x8*)(&Bs[wn + nt * 16 + l16][quad * 8]);
#pragma unroll
    for (int mt = 0; mt < 4; ++mt)
#pragma unroll
      for (int nt = 0; nt < 4; ++nt)
        acc[mt][nt] = mfma16(af[mt], bfr[nt], acc[mt][nt]);
    __syncthreads();
  }

  // out[b][s2][e2], s2 = (row&1)*1024 + col, e2 = (row&2047)>>1.
  float(*Ts)[68] = (float(*)[68])smem_raw;
  const int b = mbase >> 11;
  const int ebase = (mbase & 2047) >> 1;
#pragma unroll
  for (int p = 0; p < 2; ++p) {
    __syncthreads();
#pragma unroll
    for (int mt = 0; mt < 4; ++mt)
#pragma unroll
      for (int nt = 0; nt < 4; ++nt)
#pragma unroll
        for (int rr = p; rr < 4; rr += 2) {
          int col_local = wn + nt * 16 + l16;
          int row_local = wm + mt * 16 + quad * 4 + rr;
          Ts[col_local][row_local >> 1] = acc[mt][nt][rr];
        }
    __syncthreads();
    int srow = t >> 1;
    int e0 = (t & 1) << 5;
    float* dst = C + (size_t)b * 2097152 +
                 (size_t)(p * 1024 + nbase + srow) * 1024 + ebase + e0;
#pragma unroll
    for (int j = 0; j < 8; ++j)
      ((float4*)dst)[j] = *(const float4*)&Ts[srow][e0 + j * 4];
  }
}

// Flash attention [BH=32, S=2048, D=128]; BQ=128 (4 waves x 32 rows), BKV=64.
__global__ __launch_bounds__(256, 2) void flash_attn(const unsigned short* __restrict__ Q,
                                                     const unsigned short* __restrict__ Kg,
                                                     const unsigned short* __restrict__ Vg,
                                                     unsigned short* __restrict__ O) {
  __shared__ __align__(16) unsigned short Ks[64][136];   // [kv][d] +8 pad
  __shared__ __align__(16) unsigned short Vt[128][72];   // [d][kv] +8 pad (transposed)
  __shared__ __align__(16) unsigned short Ps[4][32][72]; // per-wave P round-trip
  const int t = threadIdx.x;
  const int lane = t & 63;
  const int wid = t >> 6;
  const int quad = lane >> 4;
  const int l16 = lane & 15;
  // XCD-aware swizzle: blocks sharing bh cluster on one XCD (i&7 = XCD hint).
  const int i = blockIdx.x;                 // [0,512)
  const int bh = (i & 7) + ((i >> 3) & 3) * 8;
  const int qbase = (i >> 5) << 7;
  const size_t base = (size_t)bh * (2048 * 128);
  const float scale = 0.3535533905932738f;  // 1/sqrt(H=8)

  // Q fragments, A-layout: m=lane&15, k=quad*8+j (+32 per ks)
  bf16x8 qf[2][4];
#pragma unroll
  for (int mt = 0; mt < 2; ++mt) {
    int row = qbase + wid * 32 + mt * 16 + l16;
#pragma unroll
    for (int ks = 0; ks < 4; ++ks)
      qf[mt][ks] = *(const bf16x8*)(Q + base + (size_t)row * 128 + ks * 32 + quad * 8);
  }

  f32x4 accO[2][8] = {};
  float mst[2][4], lst[2][4];
#pragma unroll
  for (int mt = 0; mt < 2; ++mt)
#pragma unroll
    for (int r = 0; r < 4; ++r) { mst[mt][r] = -__builtin_inff(); lst[mt][r] = 0.f; }

  for (int kv0 = 0; kv0 < 2048; kv0 += 64) {
    // stage K [64][128]
#pragma unroll
    for (int i2 = 0; i2 < 4; ++i2) {
      int c = t + (i2 << 8);
      int row = c >> 4;
      int col = (c & 15) << 3;
      *(uint4*)(&Ks[row][col]) = *(const uint4*)(Kg + base + (size_t)(kv0 + row) * 128 + col);
    }
    // stage V transposed [d][kv]; lane-staggered scalar writes
#pragma unroll
    for (int i2 = 0; i2 < 4; ++i2) {
      int c = t + (i2 << 8);
      int row = c >> 4;
      int col = (c & 15) << 3;
      __align__(16) unsigned short tmp[8];
      *(uint4*)tmp = *(const uint4*)(Vg + base + (size_t)(kv0 + row) * 128 + col);
#pragma unroll
      for (int j = 0; j < 8; ++j) {
        int jj = (j + lane) & 7;
        Vt[col + jj][row] = tmp[jj];
      }
    }
    __syncthreads();

    // S = Q K^T (raw; scale folded into exp)
    f32x4 accS[2][4];
#pragma unroll
    for (int nt = 0; nt < 4; ++nt) {
      bf16x8 kf[4];
#pragma unroll
      for (int ks = 0; ks < 4; ++ks)
        kf[ks] = *(const bf16x8*)(&Ks[nt * 16 + l16][ks * 32 + quad * 8]);
#pragma unroll
      for (int mt = 0; mt < 2; ++mt) {
        f32x4 a = {0.f, 0.f, 0.f, 0.f};
#pragma unroll
        for (int ks = 0; ks < 4; ++ks)
          a = mfma16(qf[mt][ks], kf[ks], a);
        accS[mt][nt] = a;
      }
    }

    // online softmax on raw scores; row r spans the 16 lanes of one quad group
#pragma unroll
    for (int mt = 0; mt < 2; ++mt) {
#pragma unroll
      for (int r = 0; r < 4; ++r) {
        float mx = fmaxf(fmaxf(accS[mt][0][r], accS[mt][1][r]),
                         fmaxf(accS[mt][2][r], accS[mt][3][r]));
#pragma unroll
        for (int off = 1; off < 16; off <<= 1) mx = fmaxf(mx, __shfl_xor(mx, off));
        float mnew = fmaxf(mst[mt][r], mx);
        float alpha = __expf((mst[mt][r] - mnew) * scale);
        float negms = -mnew * scale;
        float psum = 0.f;
#pragma unroll
        for (int nt = 0; nt < 4; ++nt) {
          float p = __expf(fmaf(accS[mt][nt][r], scale, negms));
          accS[mt][nt][r] = p;
          psum += p;
        }
#pragma unroll
        for (int off = 1; off < 16; off <<= 1) psum += __shfl_xor(psum, off);
        lst[mt][r] = lst[mt][r] * alpha + psum;
        mst[mt][r] = mnew;
#pragma unroll
        for (int dt = 0; dt < 8; ++dt) accO[mt][dt][r] *= alpha;
      }
    }

    // P: C-layout -> bf16 -> per-wave LDS -> A-layout (no barrier: wave-local)
#pragma unroll
    for (int mt = 0; mt < 2; ++mt)
#pragma unroll
      for (int nt = 0; nt < 4; ++nt)
#pragma unroll
        for (int r = 0; r < 4; ++r)
          Ps[wid][mt * 16 + quad * 4 + r][nt * 16 + l16] = f2bf(accS[mt][nt][r]);

    bf16x8 pf[2][2];
#pragma unroll
    for (int mt = 0; mt < 2; ++mt)
#pragma unroll
      for (int ks = 0; ks < 2; ++ks)
        pf[mt][ks] = *(const bf16x8*)(&Ps[wid][mt * 16 + l16][ks * 32 + quad * 8]);
#pragma unroll
    for (int dt = 0; dt < 8; ++dt) {
      bf16x8 vf[2];
#pragma unroll
      for (int ks = 0; ks < 2; ++ks)
        vf[ks] = *(const bf16x8*)(&Vt[dt * 16 + l16][ks * 32 + quad * 8]);
#pragma unroll
      for (int mt = 0; mt < 2; ++mt)
#pragma unroll
        for (int ks = 0; ks < 2; ++ks)
          accO[mt][dt] = mfma16(pf[mt][ks], vf[ks], accO[mt][dt]);
    }
    __syncthreads();  // guard Ks/Vt restage of next iteration
  }

#pragma unroll
  for (int mt = 0; mt < 2; ++mt) {
#pragma unroll
    for (int r = 0; r < 4; ++r) {
      float inv = 1.f / lst[mt][r];
      int row = qbase + wid * 32 + mt * 16 + quad * 4 + r;
#pragma unroll
      for (int dt = 0; dt < 8; ++dt) {
        int col = dt * 16 + l16;
        O[base + (size_t)row * 128 + col] = f2bf(accO[mt][dt][r] * inv);
      }
    }
  }
}

// o4[b,h,s,d] -> x2 rows i=h*256+d*2+(s>>10), cols j=s&1023 (RowLinear pre-shuffle)
__global__ __launch_bounds__(256) void transpose_o(const unsigned short* __restrict__ O4,
                                                   unsigned short* __restrict__ X2) {
  __shared__ __align__(16) unsigned short tile[64][72];
  const int t = threadIdx.x;
  const int s0 = blockIdx.x * 64;
  const int d0 = blockIdx.y * 64;
  const int bh = blockIdx.z;
  const int b = bh >> 3;
  const int h = bh & 7;
  const size_t src = (size_t)bh * (2048 * 128);
#pragma unroll
  for (int i = 0; i < 2; ++i) {
    int c = t + (i << 8);
    int sr = c >> 3;
    int dc = (c & 7) << 3;
    *(uint4*)(&tile[sr][dc]) = *(const uint4*)(O4 + src + (size_t)(s0 + sr) * 128 + d0 + dc);
  }
  __syncthreads();
#pragma unroll
  for (int i = 0; i < 2; ++i) {
    int c = t + (i << 8);
    int dr = c >> 3;
    int sc = (c & 7) << 3;
    __align__(16) unsigned short tmp[8];
#pragma unroll
    for (int j = 0; j < 8; ++j) tmp[j] = tile[sc + j][dr];
    int d = d0 + dr;
    int srow = s0 + sc;
    size_t dst = (size_t)b * (2048 * 1024) +
                 (size_t)(h * 256 + d * 2 + (srow >> 10)) * 1024 + (srow & 1023);
    *(uint4*)(&X2[dst]) = *(uint4*)tmp;
  }
}

extern "C" void kernel_launch(void* const* d_in, const int* in_sizes, int n_in,
                              void* d_out, int out_size, void* d_ws, size_t ws_size,
                              hipStream_t stream) {
  const float* emb = (const float*)d_in[0];
  const float* W1  = (const float*)d_in[1];
  const float* W2  = (const float*)d_in[2];
  const float* W3  = (const float*)d_in[3];
  const float* Wo  = (const float*)d_in[4];
  float* out = (float*)d_out;

  const size_t NELEM = (size_t)8 * 1024 * 1024;  // bf16 elems per [B*S, P] buffer
  unsigned short* q  = (unsigned short*)d_ws;
  unsigned short* k  = q + NELEM;
  unsigned short* v  = k + NELEM;
  unsigned short* o4 = v + NELEM;
  unsigned short* x2 = q;  // q dead after flash_attn; reuse

  dim3 blk(256, 1, 1);
  gemm_qkv<<<dim3(24, 64), blk, 0, stream>>>(emb, W1, W2, W3, q, k, v);
  flash_attn<<<dim3(512, 1, 1), blk, 0, stream>>>(q, k, v, o4);
  transpose_o<<<dim3(32, 2, 32), blk, 0, stream>>>(o4, x2);
  gemm_out<<<dim3(8, 64), blk, 0, stream>>>(x2, Wo, out);
}

// Round 6
// 392.608 us; speedup vs baseline: 4.0271x; 1.3520x over previous
//
#include <hip/hip_runtime.h>

typedef float f32x4 __attribute__((ext_vector_type(4)));
typedef __bf16 bf16x8 __attribute__((ext_vector_type(8)));

__device__ __forceinline__ unsigned short f2bf(float f) {
  unsigned int u = __float_as_uint(f);
  u = (u + 0x7FFFu + ((u >> 16) & 1u)) >> 16;
  return (unsigned short)u;
}

__device__ __forceinline__ f32x4 mfma16(bf16x8 a, bf16x8 b, f32x4 c) {
  return __builtin_amdgcn_mfma_f32_16x16x32_bf16(a, b, c, 0, 0, 0);
}

__device__ __forceinline__ void load8_bf16(const unsigned short* p, unsigned short* d) {
  *(uint4*)d = *(const uint4*)p;
}
__device__ __forceinline__ void load8_bf16(const float* p, unsigned short* d) {
  float4 a = *(const float4*)p;
  float4 b = *(const float4*)(p + 4);
  __align__(16) unsigned short t[8] = {f2bf(a.x), f2bf(a.y), f2bf(a.z), f2bf(a.w),
                                       f2bf(b.x), f2bf(b.y), f2bf(b.z), f2bf(b.w)};
  *(uint4*)d = *(uint4*)t;
}

// Fused QKV projection. blockIdx.x in [0,24): sel = x>>3 (0:q, 1:k, 2:v), nb=(x&7)*128.
// q,k: RoPE epilogue; v: plain natural store ([B*S,P] flat == view [bh][s][d]).
__global__ __launch_bounds__(256) void gemm_qkv(const float* __restrict__ A,
                                                const float* __restrict__ W1,
                                                const float* __restrict__ W2,
                                                const float* __restrict__ W3,
                                                unsigned short* __restrict__ q,
                                                unsigned short* __restrict__ k,
                                                unsigned short* __restrict__ v) {
  __shared__ __align__(16) unsigned short As[128][40];
  __shared__ __align__(16) unsigned short Bs[128][40];
  const int t = threadIdx.x;
  const int lane = t & 63;
  const int wid = t >> 6;
  const int quad = lane >> 4;
  const int l16 = lane & 15;
  const int wm = (wid >> 1) << 6;
  const int wn = (wid & 1) << 6;
  const int sel = blockIdx.x >> 3;
  const int nb = (blockIdx.x & 7) << 7;
  const int mbase = blockIdx.y * 128;
  const float* Bt = (sel == 0) ? W1 : (sel == 1) ? W2 : W3;
  unsigned short* C = (sel == 0) ? q : (sel == 1) ? k : v;

  f32x4 acc[4][4] = {};

  for (int k0 = 0; k0 < 1024; k0 += 32) {
#pragma unroll
    for (int i = 0; i < 2; ++i) {
      int c = t + (i << 8);
      int row = c >> 2;
      int col = (c & 3) << 3;
      load8_bf16(A + (size_t)(mbase + row) * 1024 + k0 + col, &As[row][col]);
      load8_bf16(Bt + (size_t)(nb + row) * 1024 + k0 + col, &Bs[row][col]);
    }
    __syncthreads();
    bf16x8 af[4], bfr[4];
#pragma unroll
    for (int mt = 0; mt < 4; ++mt)
      af[mt] = *(const bf16x8*)(&As[wm + mt * 16 + l16][quad * 8]);
#pragma unroll
    for (int nt = 0; nt < 4; ++nt)
      bfr[nt] = *(const bf16x8*)(&Bs[wn + nt * 16 + l16][quad * 8]);
#pragma unroll
    for (int mt = 0; mt < 4; ++mt)
#pragma unroll
      for (int nt = 0; nt < 4; ++nt)
        acc[mt][nt] = mfma16(af[mt], bfr[nt], acc[mt][nt]);
    __syncthreads();
  }

  const bool rope = (sel < 2);
#pragma unroll
  for (int mt = 0; mt < 4; ++mt) {
#pragma unroll
    for (int nt = 0; nt < 4; ++nt) {
#pragma unroll
      for (int r = 0; r < 4; ++r) {
        int row_g = mbase + wm + mt * 16 + quad * 4 + r;
        int col_g = nb + wn + nt * 16 + l16;
        float val = acc[mt][nt][r];
        if (rope) {  // interleaved RoPE; partner col = col^1 lives in lane^1
          float other = __shfl_xor(val, 1);
          int s = (((row_g & 2047) << 3) + (col_g >> 7)) & 2047;  // view-seq position
          int d = col_g & 127;
          float invf = __expf(-0.14391156f * (float)(d >> 1));  // ln(1e4)/64
          float ang = (float)s * invf;
          float sv, cv;
          __sincosf(ang, &sv, &cv);
          val = (d & 1) ? (val * cv + other * sv) : (val * cv - other * sv);
        }
        C[(size_t)row_g * 1024 + col_g] = f2bf(val);
      }
    }
  }
}

// Plain per-bh transpose: vT[bh][d][s] = v[bh][s][d]. Both are flat-view buffers.
__global__ __launch_bounds__(256) void transpose_v(const unsigned short* __restrict__ Vn,
                                                   unsigned short* __restrict__ VT) {
  __shared__ __align__(16) unsigned short tile[64][72];
  const int t = threadIdx.x;
  const int s0 = blockIdx.x * 64;
  const int d0 = blockIdx.y * 64;
  const int bh = blockIdx.z;
  const size_t base = (size_t)bh * (2048 * 128);
#pragma unroll
  for (int i = 0; i < 2; ++i) {
    int c = t + (i << 8);
    int sr = c >> 3;
    int dc = (c & 7) << 3;
    *(uint4*)(&tile[sr][dc]) = *(const uint4*)(Vn + base + (size_t)(s0 + sr) * 128 + d0 + dc);
  }
  __syncthreads();
#pragma unroll
  for (int i = 0; i < 2; ++i) {
    int c = t + (i << 8);
    int dr = c >> 3;
    int sc = (c & 7) << 3;
    __align__(16) unsigned short tmp[8];
#pragma unroll
    for (int j = 0; j < 8; ++j) tmp[j] = tile[sc + j][dr];
    *(uint4*)(VT + base + (size_t)(d0 + dr) * 2048 + s0 + sc) = *(uint4*)tmp;
  }
}

// Final projection. A-tile rows remap the RowLinear pre-shuffle onto oT[bh][d][s]
// (contiguous in k-dim), output-permutation fp32 store (LDS transposed, coalesced).
__global__ __launch_bounds__(256) void gemm_out(const unsigned short* __restrict__ OT,
                                                const float* __restrict__ Bt,
                                                float* __restrict__ C) {
  __shared__ __align__(16) char smem_raw[128 * 68 * 4];
  auto As = (unsigned short(*)[40])smem_raw;
  auto Bs = (unsigned short(*)[40])(smem_raw + 128 * 40 * 2);
  const int t = threadIdx.x;
  const int lane = t & 63;
  const int wid = t >> 6;
  const int quad = lane >> 4;
  const int l16 = lane & 15;
  const int wm = (wid >> 1) << 6;
  const int wn = (wid & 1) << 6;
  const int mbase = blockIdx.y * 128;
  const int nbase = blockIdx.x * 128;

  f32x4 acc[4][4] = {};

  for (int k0 = 0; k0 < 1024; k0 += 32) {
#pragma unroll
    for (int i = 0; i < 2; ++i) {
      int c = t + (i << 8);
      int row = c >> 2;
      int col = (c & 3) << 3;
      // x2 row R: b=R>>11, i=R&2047; x2[R][j] = oT[b*8+(i>>8)][(i>>1)&127][(i&1)*1024+j]
      int R = mbase + row;
      int b = R >> 11;
      int ii = R & 2047;
      const unsigned short* src = OT + (size_t)(b * 8 + (ii >> 8)) * (128 * 2048) +
                                  (size_t)((ii >> 1) & 127) * 2048 + ((ii & 1) << 10) +
                                  k0 + col;
      load8_bf16(src, &As[row][col]);
      load8_bf16(Bt + (size_t)(nbase + row) * 1024 + k0 + col, &Bs[row][col]);
    }
    __syncthreads();
    bf16x8 af[4], bfr[4];
#pragma unroll
    for (int mt = 0; mt < 4; ++mt)
      af[mt] = *(const bf16x8*)(&As[wm + mt * 16 + l16][quad * 8]);
#pragma unroll
    for (int nt = 0; nt < 4; ++nt)
      bfr[nt] = *(const bf16x8*)(&Bs[wn + nt * 16 + l16][quad * 8]);
#pragma unroll
    for (int mt = 0; mt < 4; ++mt)
#pragma unroll
      for (int nt = 0; nt < 4; ++nt)
        acc[mt][nt] = mfma16(af[mt], bfr[nt], acc[mt][nt]);
    __syncthreads();
  }

  // out[b][s2][e2], s2 = (row&1)*1024 + col, e2 = (row&2047)>>1.
  float(*Ts)[68] = (float(*)[68])smem_raw;
  const int b = mbase >> 11;
  const int ebase = (mbase & 2047) >> 1;
#pragma unroll
  for (int p = 0; p < 2; ++p) {
    __syncthreads();
#pragma unroll
    for (int mt = 0; mt < 4; ++mt)
#pragma unroll
      for (int nt = 0; nt < 4; ++nt)
#pragma unroll
        for (int rr = p; rr < 4; rr += 2) {
          int col_local = wn + nt * 16 + l16;
          int row_local = wm + mt * 16 + quad * 4 + rr;
          Ts[col_local][row_local >> 1] = acc[mt][nt][rr];
        }
    __syncthreads();
    int srow = t >> 1;
    int e0 = (t & 1) << 5;
    float* dst = C + (size_t)b * 2097152 +
                 (size_t)(p * 1024 + nbase + srow) * 1024 + ebase + e0;
#pragma unroll
    for (int j = 0; j < 8; ++j)
      ((float4*)dst)[j] = *(const float4*)&Ts[srow][e0 + j * 4];
  }
}

// Flash attention [BH=32, S=2048, D=128]; BQ=128 (4 waves x 32 rows), BKV=64.
// V input pre-transposed (vT[bh][d][s]); O output written transposed (oT[bh][d][s]).
__global__ __launch_bounds__(256, 2) void flash_attn(const unsigned short* __restrict__ Q,
                                                     const unsigned short* __restrict__ Kg,
                                                     const unsigned short* __restrict__ VTg,
                                                     unsigned short* __restrict__ OT) {
  // Ks 64x136x2=17408 | Vt 128x72x2=18432 | Ps 4x32x72x2=18432  (total 54272)
  // epilogue: To 128x136x2=34816 aliases Ks+Vt
  __shared__ __align__(16) char sm[54272];
  auto Ks = (unsigned short(*)[136])sm;
  auto Vt = (unsigned short(*)[72])(sm + 17408);
  auto Ps = (unsigned short(*)[32][72])(sm + 35840);
  const int t = threadIdx.x;
  const int lane = t & 63;
  const int wid = t >> 6;
  const int quad = lane >> 4;
  const int l16 = lane & 15;
  const int i = blockIdx.x;                 // [0,512); XCD-aware swizzle
  const int bh = (i & 7) + ((i >> 3) & 3) * 8;
  const int qbase = (i >> 5) << 7;
  const size_t base = (size_t)bh * (2048 * 128);
  const float scale = 0.3535533905932738f;  // 1/sqrt(H=8)

  // Q fragments, A-layout: m=lane&15, k=quad*8+j (+32 per ks)
  bf16x8 qf[2][4];
#pragma unroll
  for (int mt = 0; mt < 2; ++mt) {
    int row = qbase + wid * 32 + mt * 16 + l16;
#pragma unroll
    for (int ks = 0; ks < 4; ++ks)
      qf[mt][ks] = *(const bf16x8*)(Q + base + (size_t)row * 128 + ks * 32 + quad * 8);
  }

  f32x4 accO[2][8] = {};
  float mst[2][4], lst[2][4];
#pragma unroll
  for (int mt = 0; mt < 2; ++mt)
#pragma unroll
    for (int r = 0; r < 4; ++r) { mst[mt][r] = -__builtin_inff(); lst[mt][r] = 0.f; }

  for (int kv0 = 0; kv0 < 2048; kv0 += 64) {
    // stage K [kv 64][d 128]
#pragma unroll
    for (int i2 = 0; i2 < 4; ++i2) {
      int c = t + (i2 << 8);
      int row = c >> 4;
      int col = (c & 15) << 3;
      *(uint4*)(&Ks[row][col]) = *(const uint4*)(Kg + base + (size_t)(kv0 + row) * 128 + col);
    }
    // stage V^T [d 128][kv 64] straight from vT (vector copies, no transpose)
#pragma unroll
    for (int i2 = 0; i2 < 4; ++i2) {
      int c = t + (i2 << 8);
      int row = c >> 3;            // d
      int col = (c & 7) << 3;      // kv chunk
      *(uint4*)(&Vt[row][col]) =
          *(const uint4*)(VTg + base + (size_t)row * 2048 + kv0 + col);
    }
    __syncthreads();

    // S = Q K^T (raw; scale folded into exp)
    f32x4 accS[2][4];
#pragma unroll
    for (int nt = 0; nt < 4; ++nt) {
      bf16x8 kf[4];
#pragma unroll
      for (int ks = 0; ks < 4; ++ks)
        kf[ks] = *(const bf16x8*)(&Ks[nt * 16 + l16][ks * 32 + quad * 8]);
#pragma unroll
      for (int mt = 0; mt < 2; ++mt) {
        f32x4 a = {0.f, 0.f, 0.f, 0.f};
#pragma unroll
        for (int ks = 0; ks < 4; ++ks)
          a = mfma16(qf[mt][ks], kf[ks], a);
        accS[mt][nt] = a;
      }
    }

    // online softmax; row r spans the 16 lanes of one quad group
#pragma unroll
    for (int mt = 0; mt < 2; ++mt) {
#pragma unroll
      for (int r = 0; r < 4; ++r) {
        float mx = fmaxf(fmaxf(accS[mt][0][r], accS[mt][1][r]),
                         fmaxf(accS[mt][2][r], accS[mt][3][r]));
#pragma unroll
        for (int off = 1; off < 16; off <<= 1) mx = fmaxf(mx, __shfl_xor(mx, off));
        float mnew = fmaxf(mst[mt][r], mx);
        float alpha = __expf((mst[mt][r] - mnew) * scale);
        float negms = -mnew * scale;
        float psum = 0.f;
#pragma unroll
        for (int nt = 0; nt < 4; ++nt) {
          float p = __expf(fmaf(accS[mt][nt][r], scale, negms));
          accS[mt][nt][r] = p;
          psum += p;
        }
#pragma unroll
        for (int off = 1; off < 16; off <<= 1) psum += __shfl_xor(psum, off);
        lst[mt][r] = lst[mt][r] * alpha + psum;
        mst[mt][r] = mnew;
#pragma unroll
        for (int dt = 0; dt < 8; ++dt) accO[mt][dt][r] *= alpha;
      }
    }

    // P: C-layout -> bf16 -> per-wave LDS -> A-layout (no barrier: wave-local)
#pragma unroll
    for (int mt = 0; mt < 2; ++mt)
#pragma unroll
      for (int nt = 0; nt < 4; ++nt)
#pragma unroll
        for (int r = 0; r < 4; ++r)
          Ps[wid][mt * 16 + quad * 4 + r][nt * 16 + l16] = f2bf(accS[mt][nt][r]);

    bf16x8 pf[2][2];
#pragma unroll
    for (int mt = 0; mt < 2; ++mt)
#pragma unroll
      for (int ks = 0; ks < 2; ++ks)
        pf[mt][ks] = *(const bf16x8*)(&Ps[wid][mt * 16 + l16][ks * 32 + quad * 8]);
#pragma unroll
    for (int dt = 0; dt < 8; ++dt) {
      bf16x8 vf[2];
#pragma unroll
      for (int ks = 0; ks < 2; ++ks)
        vf[ks] = *(const bf16x8*)(&Vt[dt * 16 + l16][ks * 32 + quad * 8]);
#pragma unroll
      for (int mt = 0; mt < 2; ++mt)
#pragma unroll
        for (int ks = 0; ks < 2; ++ks)
          accO[mt][dt] = mfma16(pf[mt][ks], vf[ks], accO[mt][dt]);
    }
    __syncthreads();  // guard Ks/Vt restage of next iteration (and epilogue alias)
  }

  // Epilogue: O^T via LDS transpose (To aliases Ks/Vt; last loop barrier guards it)
  auto To = (unsigned short(*)[136])sm;  // [d 128][s_local 128]
#pragma unroll
  for (int mt = 0; mt < 2; ++mt) {
#pragma unroll
    for (int r = 0; r < 4; ++r) {
      float inv = 1.f / lst[mt][r];
      int srow = wid * 32 + mt * 16 + quad * 4 + r;
#pragma unroll
      for (int dt = 0; dt < 8; ++dt)
        To[dt * 16 + l16][srow] = f2bf(accO[mt][dt][r] * inv);
    }
  }
  __syncthreads();
  int dr = t >> 1;
  int off = (t & 1) << 6;
  unsigned short* dst = OT + base + (size_t)dr * 2048 + qbase + off;
#pragma unroll
  for (int j = 0; j < 8; ++j)
    ((uint4*)dst)[j] = *(const uint4*)&To[dr][off + j * 8];
}

extern "C" void kernel_launch(void* const* d_in, const int* in_sizes, int n_in,
                              void* d_out, int out_size, void* d_ws, size_t ws_size,
                              hipStream_t stream) {
  const float* emb = (const float*)d_in[0];
  const float* W1  = (const float*)d_in[1];
  const float* W2  = (const float*)d_in[2];
  const float* W3  = (const float*)d_in[3];
  const float* Wo  = (const float*)d_in[4];
  float* out = (float*)d_out;

  const size_t NELEM = (size_t)8 * 1024 * 1024;  // bf16 elems per [B*S, P] buffer
  unsigned short* q  = (unsigned short*)d_ws;
  unsigned short* k  = q + NELEM;
  unsigned short* vn = k + NELEM;   // natural V
  unsigned short* vT = vn + NELEM;  // transposed V
  unsigned short* oT = vn;          // vn dead after transpose_v; reuse (64 MB total)

  dim3 blk(256, 1, 1);
  gemm_qkv<<<dim3(24, 64), blk, 0, stream>>>(emb, W1, W2, W3, q, k, vn);
  transpose_v<<<dim3(32, 2, 32), blk, 0, stream>>>(vn, vT);
  flash_attn<<<dim3(512, 1, 1), blk, 0, stream>>>(q, k, vT, oT);
  gemm_out<<<dim3(8, 64), blk, 0, stream>>>(oT, Wo, out);
}

// Round 7
// 366.193 us; speedup vs baseline: 4.3176x; 1.0721x over previous
//
#include <hip/hip_runtime.h>

typedef float f32x4 __attribute__((ext_vector_type(4)));
typedef __bf16 bf16x8 __attribute__((ext_vector_type(8)));

__device__ __forceinline__ unsigned short f2bf(float f) {
  unsigned int u = __float_as_uint(f);
  u = (u + 0x7FFFu + ((u >> 16) & 1u)) >> 16;
  return (unsigned short)u;
}

__device__ __forceinline__ f32x4 mfma16(bf16x8 a, bf16x8 b, f32x4 c) {
  return __builtin_amdgcn_mfma_f32_16x16x32_bf16(a, b, c, 0, 0, 0);
}

__device__ __forceinline__ void load8_bf16(const unsigned short* p, unsigned short* d) {
  *(uint4*)d = *(const uint4*)p;
}
__device__ __forceinline__ void load8_bf16(const float* p, unsigned short* d) {
  float4 a = *(const float4*)p;
  float4 b = *(const float4*)(p + 4);
  __align__(16) unsigned short t[8] = {f2bf(a.x), f2bf(a.y), f2bf(a.z), f2bf(a.w),
                                       f2bf(b.x), f2bf(b.y), f2bf(b.z), f2bf(b.w)};
  *(uint4*)d = *(uint4*)t;
}

// fp32 -> bf16, 8 elems/thread. n8 = n/2048 blocks of 256 threads.
__global__ __launch_bounds__(256) void convert_gen(const float* __restrict__ src,
                                                   unsigned short* __restrict__ dst) {
  int idx = (blockIdx.x * 256 + threadIdx.x) * 8;
  __align__(16) unsigned short t[8];
  load8_bf16(src + idx, t);
  *(uint4*)(dst + idx) = *(uint4*)t;
}

// W1|W2|W3 (each 1M fp32) -> contiguous bf16. 1536 blocks.
__global__ __launch_bounds__(256) void convert_w3(const float* __restrict__ W1,
                                                  const float* __restrict__ W2,
                                                  const float* __restrict__ W3,
                                                  unsigned short* __restrict__ dst) {
  int i = blockIdx.x;
  int sel = i >> 9;
  const float* src = (sel == 0) ? W1 : (sel == 1) ? W2 : W3;
  int off = (i & 511) * 2048 + threadIdx.x * 8;
  __align__(16) unsigned short t[8];
  load8_bf16(src + off, t);
  *(uint4*)(dst + sel * 1048576 + off) = *(uint4*)t;
}

// Fused QKV projection. blockIdx.x in [0,24): sel = x>>3 (0:q,1:k,2:v), nb=(x&7)*128.
// B from pre-converted bf16 weights. q,k: RoPE epilogue; v: natural store.
template <typename TA>
__global__ __launch_bounds__(256) void gemm_qkv(const TA* __restrict__ A,
                                                const unsigned short* __restrict__ WB,
                                                unsigned short* __restrict__ q,
                                                unsigned short* __restrict__ k,
                                                unsigned short* __restrict__ v) {
  __shared__ __align__(16) unsigned short As[128][40];
  __shared__ __align__(16) unsigned short Bs[128][40];
  const int t = threadIdx.x;
  const int lane = t & 63;
  const int wid = t >> 6;
  const int quad = lane >> 4;
  const int l16 = lane & 15;
  const int wm = (wid >> 1) << 6;
  const int wn = (wid & 1) << 6;
  const int sel = blockIdx.x >> 3;
  const int nb = (blockIdx.x & 7) << 7;
  const int mbase = blockIdx.y * 128;
  const unsigned short* Bt = WB + sel * 1048576;
  unsigned short* C = (sel == 0) ? q : (sel == 1) ? k : v;

  f32x4 acc[4][4] = {};

  for (int k0 = 0; k0 < 1024; k0 += 32) {
#pragma unroll
    for (int i = 0; i < 2; ++i) {
      int c = t + (i << 8);
      int row = c >> 2;
      int col = (c & 3) << 3;
      load8_bf16(A + (size_t)(mbase + row) * 1024 + k0 + col, &As[row][col]);
      load8_bf16(Bt + (size_t)(nb + row) * 1024 + k0 + col, &Bs[row][col]);
    }
    __syncthreads();
    bf16x8 af[4], bfr[4];
#pragma unroll
    for (int mt = 0; mt < 4; ++mt)
      af[mt] = *(const bf16x8*)(&As[wm + mt * 16 + l16][quad * 8]);
#pragma unroll
    for (int nt = 0; nt < 4; ++nt)
      bfr[nt] = *(const bf16x8*)(&Bs[wn + nt * 16 + l16][quad * 8]);
#pragma unroll
    for (int mt = 0; mt < 4; ++mt)
#pragma unroll
      for (int nt = 0; nt < 4; ++nt)
        acc[mt][nt] = mfma16(af[mt], bfr[nt], acc[mt][nt]);
    __syncthreads();
  }

  const bool rope = (sel < 2);
#pragma unroll
  for (int mt = 0; mt < 4; ++mt) {
#pragma unroll
    for (int nt = 0; nt < 4; ++nt) {
#pragma unroll
      for (int r = 0; r < 4; ++r) {
        int row_g = mbase + wm + mt * 16 + quad * 4 + r;
        int col_g = nb + wn + nt * 16 + l16;
        float val = acc[mt][nt][r];
        if (rope) {  // interleaved RoPE; partner col = col^1 lives in lane^1
          float other = __shfl_xor(val, 1);
          int s = (((row_g & 2047) << 3) + (col_g >> 7)) & 2047;  // view-seq position
          int d = col_g & 127;
          float invf = __expf(-0.14391156f * (float)(d >> 1));  // ln(1e4)/64
          float ang = (float)s * invf;
          float sv, cv;
          __sincosf(ang, &sv, &cv);
          val = (d & 1) ? (val * cv + other * sv) : (val * cv - other * sv);
        }
        C[(size_t)row_g * 1024 + col_g] = f2bf(val);
      }
    }
  }
}

// Plain per-bh transpose: vT[bh][d][s] = v[bh][s][d].
__global__ __launch_bounds__(256) void transpose_v(const unsigned short* __restrict__ Vn,
                                                   unsigned short* __restrict__ VT) {
  __shared__ __align__(16) unsigned short tile[64][72];
  const int t = threadIdx.x;
  const int s0 = blockIdx.x * 64;
  const int d0 = blockIdx.y * 64;
  const int bh = blockIdx.z;
  const size_t base = (size_t)bh * (2048 * 128);
#pragma unroll
  for (int i = 0; i < 2; ++i) {
    int c = t + (i << 8);
    int sr = c >> 3;
    int dc = (c & 7) << 3;
    *(uint4*)(&tile[sr][dc]) = *(const uint4*)(Vn + base + (size_t)(s0 + sr) * 128 + d0 + dc);
  }
  __syncthreads();
#pragma unroll
  for (int i = 0; i < 2; ++i) {
    int c = t + (i << 8);
    int dr = c >> 3;
    int sc = (c & 7) << 3;
    __align__(16) unsigned short tmp[8];
#pragma unroll
    for (int j = 0; j < 8; ++j) tmp[j] = tile[sc + j][dr];
    *(uint4*)(VT + base + (size_t)(d0 + dr) * 2048 + s0 + sc) = *(uint4*)tmp;
  }
}

// Final projection. A rows remap RowLinear pre-shuffle onto oT[bh][d][s];
// B pre-converted bf16; output-permutation fp32 store (LDS transposed, coalesced).
__global__ __launch_bounds__(256) void gemm_out(const unsigned short* __restrict__ OT,
                                                const unsigned short* __restrict__ Bt,
                                                float* __restrict__ C) {
  __shared__ __align__(16) char smem_raw[128 * 68 * 4];
  auto As = (unsigned short(*)[40])smem_raw;
  auto Bs = (unsigned short(*)[40])(smem_raw + 128 * 40 * 2);
  const int t = threadIdx.x;
  const int lane = t & 63;
  const int wid = t >> 6;
  const int quad = lane >> 4;
  const int l16 = lane & 15;
  const int wm = (wid >> 1) << 6;
  const int wn = (wid & 1) << 6;
  const int mbase = blockIdx.y * 128;
  const int nbase = blockIdx.x * 128;

  f32x4 acc[4][4] = {};

  for (int k0 = 0; k0 < 1024; k0 += 32) {
#pragma unroll
    for (int i = 0; i < 2; ++i) {
      int c = t + (i << 8);
      int row = c >> 2;
      int col = (c & 3) << 3;
      int R = mbase + row;
      int b = R >> 11;
      int ii = R & 2047;
      const unsigned short* src = OT + (size_t)(b * 8 + (ii >> 8)) * (128 * 2048) +
                                  (size_t)((ii >> 1) & 127) * 2048 + ((ii & 1) << 10) +
                                  k0 + col;
      load8_bf16(src, &As[row][col]);
      load8_bf16(Bt + (size_t)(nbase + row) * 1024 + k0 + col, &Bs[row][col]);
    }
    __syncthreads();
    bf16x8 af[4], bfr[4];
#pragma unroll
    for (int mt = 0; mt < 4; ++mt)
      af[mt] = *(const bf16x8*)(&As[wm + mt * 16 + l16][quad * 8]);
#pragma unroll
    for (int nt = 0; nt < 4; ++nt)
      bfr[nt] = *(const bf16x8*)(&Bs[wn + nt * 16 + l16][quad * 8]);
#pragma unroll
    for (int mt = 0; mt < 4; ++mt)
#pragma unroll
      for (int nt = 0; nt < 4; ++nt)
        acc[mt][nt] = mfma16(af[mt], bfr[nt], acc[mt][nt]);
    __syncthreads();
  }

  // out[b][s2][e2], s2 = (row&1)*1024 + col, e2 = (row&2047)>>1.
  float(*Ts)[68] = (float(*)[68])smem_raw;
  const int b = mbase >> 11;
  const int ebase = (mbase & 2047) >> 1;
#pragma unroll
  for (int p = 0; p < 2; ++p) {
    __syncthreads();
#pragma unroll
    for (int mt = 0; mt < 4; ++mt)
#pragma unroll
      for (int nt = 0; nt < 4; ++nt)
#pragma unroll
        for (int rr = p; rr < 4; rr += 2) {
          int col_local = wn + nt * 16 + l16;
          int row_local = wm + mt * 16 + quad * 4 + rr;
          Ts[col_local][row_local >> 1] = acc[mt][nt][rr];
        }
    __syncthreads();
    int srow = t >> 1;
    int e0 = (t & 1) << 5;
    float* dst = C + (size_t)b * 2097152 +
                 (size_t)(p * 1024 + nbase + srow) * 1024 + ebase + e0;
#pragma unroll
    for (int j = 0; j < 8; ++j)
      ((float4*)dst)[j] = *(const float4*)&Ts[srow][e0 + j * 4];
  }
}

// Flash attention [BH=32, S=2048, D=128]; BQ=128 (4 waves x 32 rows), BKV=64.
// V pre-transposed (vT[bh][d][s]); O written transposed (oT[bh][d][s]).
// Row-sum l computed by MFMA with all-ones B fragment (no shuffle reduce).
__global__ __launch_bounds__(256, 2) void flash_attn(const unsigned short* __restrict__ Q,
                                                     const unsigned short* __restrict__ Kg,
                                                     const unsigned short* __restrict__ VTg,
                                                     unsigned short* __restrict__ OT) {
  // Ks 64x136x2=17408 | Vt 128x72x2=18432 | Ps 4x32x72x2=18432 (54272)
  // epilogue: To 128x136x2=34816 aliases Ks+Vt
  __shared__ __align__(16) char sm[54272];
  auto Ks = (unsigned short(*)[136])sm;
  auto Vt = (unsigned short(*)[72])(sm + 17408);
  auto Ps = (unsigned short(*)[32][72])(sm + 35840);
  const int t = threadIdx.x;
  const int lane = t & 63;
  const int wid = t >> 6;
  const int quad = lane >> 4;
  const int l16 = lane & 15;
  const int i = blockIdx.x;                 // [0,512); XCD-aware swizzle
  const int bh = (i & 7) + ((i >> 3) & 3) * 8;
  const int qbase = (i >> 5) << 7;
  const size_t base = (size_t)bh * (2048 * 128);
  const float scale = 0.3535533905932738f;  // 1/sqrt(H=8)

  bf16x8 ones8;
#pragma unroll
  for (int j = 0; j < 8; ++j) ones8[j] = (__bf16)1.0f;

  // Q fragments, A-layout: m=lane&15, k=quad*8+j (+32 per ks)
  bf16x8 qf[2][4];
#pragma unroll
  for (int mt = 0; mt < 2; ++mt) {
    int row = qbase + wid * 32 + mt * 16 + l16;
#pragma unroll
    for (int ks = 0; ks < 4; ++ks)
      qf[mt][ks] = *(const bf16x8*)(Q + base + (size_t)row * 128 + ks * 32 + quad * 8);
  }

  f32x4 accO[2][8] = {};
  f32x4 accL[2] = {};
  float mst[2][4];
#pragma unroll
  for (int mt = 0; mt < 2; ++mt)
#pragma unroll
    for (int r = 0; r < 4; ++r) mst[mt][r] = -__builtin_inff();

  for (int kv0 = 0; kv0 < 2048; kv0 += 64) {
    // stage K [kv 64][d 128]
#pragma unroll
    for (int i2 = 0; i2 < 4; ++i2) {
      int c = t + (i2 << 8);
      int row = c >> 4;
      int col = (c & 15) << 3;
      *(uint4*)(&Ks[row][col]) = *(const uint4*)(Kg + base + (size_t)(kv0 + row) * 128 + col);
    }
    // stage V^T [d 128][kv 64] from vT (pure vector copies)
#pragma unroll
    for (int i2 = 0; i2 < 4; ++i2) {
      int c = t + (i2 << 8);
      int row = c >> 3;
      int col = (c & 7) << 3;
      *(uint4*)(&Vt[row][col]) =
          *(const uint4*)(VTg + base + (size_t)row * 2048 + kv0 + col);
    }
    __syncthreads();

    // S = Q K^T (raw; scale folded into exp)
    f32x4 accS[2][4];
#pragma unroll
    for (int nt = 0; nt < 4; ++nt) {
      bf16x8 kf[4];
#pragma unroll
      for (int ks = 0; ks < 4; ++ks)
        kf[ks] = *(const bf16x8*)(&Ks[nt * 16 + l16][ks * 32 + quad * 8]);
#pragma unroll
      for (int mt = 0; mt < 2; ++mt) {
        f32x4 a = {0.f, 0.f, 0.f, 0.f};
#pragma unroll
        for (int ks = 0; ks < 4; ++ks)
          a = mfma16(qf[mt][ks], kf[ks], a);
        accS[mt][nt] = a;
      }
    }

    // online softmax (max only; sum via ones-MFMA below)
#pragma unroll
    for (int mt = 0; mt < 2; ++mt) {
#pragma unroll
      for (int r = 0; r < 4; ++r) {
        float mx = fmaxf(fmaxf(accS[mt][0][r], accS[mt][1][r]),
                         fmaxf(accS[mt][2][r], accS[mt][3][r]));
#pragma unroll
        for (int off = 1; off < 16; off <<= 1) mx = fmaxf(mx, __shfl_xor(mx, off));
        float mnew = fmaxf(mst[mt][r], mx);
        float alpha = __expf((mst[mt][r] - mnew) * scale);
        float negms = -mnew * scale;
#pragma unroll
        for (int nt = 0; nt < 4; ++nt)
          accS[mt][nt][r] = __expf(fmaf(accS[mt][nt][r], scale, negms));
        mst[mt][r] = mnew;
        accL[mt][r] *= alpha;
#pragma unroll
        for (int dt = 0; dt < 8; ++dt) accO[mt][dt][r] *= alpha;
      }
    }

    // P: C-layout -> bf16 -> per-wave LDS -> A-layout (wave-local, no barrier)
#pragma unroll
    for (int mt = 0; mt < 2; ++mt)
#pragma unroll
      for (int nt = 0; nt < 4; ++nt)
#pragma unroll
        for (int r = 0; r < 4; ++r)
          Ps[wid][mt * 16 + quad * 4 + r][nt * 16 + l16] = f2bf(accS[mt][nt][r]);

    bf16x8 pf[2][2];
#pragma unroll
    for (int mt = 0; mt < 2; ++mt)
#pragma unroll
      for (int ks = 0; ks < 2; ++ks)
        pf[mt][ks] = *(const bf16x8*)(&Ps[wid][mt * 16 + l16][ks * 32 + quad * 8]);

    // l update: row-sum of P via ones-fragment MFMA (broadcasts psum to all lanes)
#pragma unroll
    for (int mt = 0; mt < 2; ++mt)
#pragma unroll
      for (int ks = 0; ks < 2; ++ks)
        accL[mt] = mfma16(pf[mt][ks], ones8, accL[mt]);

#pragma unroll
    for (int dt = 0; dt < 8; ++dt) {
      bf16x8 vf[2];
#pragma unroll
      for (int ks = 0; ks < 2; ++ks)
        vf[ks] = *(const bf16x8*)(&Vt[dt * 16 + l16][ks * 32 + quad * 8]);
#pragma unroll
      for (int mt = 0; mt < 2; ++mt)
#pragma unroll
        for (int ks = 0; ks < 2; ++ks)
          accO[mt][dt] = mfma16(pf[mt][ks], vf[ks], accO[mt][dt]);
    }
    __syncthreads();  // guard Ks/Vt restage (and epilogue alias)
  }

  // Epilogue: O^T via LDS transpose (To aliases Ks/Vt)
  auto To = (unsigned short(*)[136])sm;  // [d 128][s_local 128]
#pragma unroll
  for (int mt = 0; mt < 2; ++mt) {
#pragma unroll
    for (int r = 0; r < 4; ++r) {
      float inv = 1.f / accL[mt][r];
      int srow = wid * 32 + mt * 16 + quad * 4 + r;
#pragma unroll
      for (int dt = 0; dt < 8; ++dt)
        To[dt * 16 + l16][srow] = f2bf(accO[mt][dt][r] * inv);
    }
  }
  __syncthreads();
  int dr = t >> 1;
  int off = (t & 1) << 6;
  unsigned short* dst = OT + base + (size_t)dr * 2048 + qbase + off;
#pragma unroll
  for (int j = 0; j < 8; ++j)
    ((uint4*)dst)[j] = *(const uint4*)&To[dr][off + j * 8];
}

extern "C" void kernel_launch(void* const* d_in, const int* in_sizes, int n_in,
                              void* d_out, int out_size, void* d_ws, size_t ws_size,
                              hipStream_t stream) {
  const float* emb = (const float*)d_in[0];
  const float* W1  = (const float*)d_in[1];
  const float* W2  = (const float*)d_in[2];
  const float* W3  = (const float*)d_in[3];
  const float* Wo  = (const float*)d_in[4];
  float* out = (float*)d_out;

  const size_t NELEM = (size_t)8 * 1024 * 1024;  // bf16 elems per [B*S, P] buffer
  unsigned short* q    = (unsigned short*)d_ws;          // [0,16) MB
  unsigned short* k    = q + NELEM;                      // [16,32)
  unsigned short* vn   = k + NELEM;                      // [32,48); later oT
  unsigned short* X    = vn + NELEM;                     // [48,64); W123B -> vT -> WoB
  unsigned short* oT   = vn;
  unsigned short* vT   = X;
  unsigned short* W123B = X;   // 6 MB, dead before transpose_v writes vT
  unsigned short* WoB  = X;    // 2 MB, written after flash (vT dead)
  unsigned short* embB = X + NELEM * 2;                  // [64,80) if ws allows

  const bool use_embB = ws_size >= (size_t)80 * 1024 * 1024;

  dim3 blk(256, 1, 1);
  convert_w3<<<dim3(1536), blk, 0, stream>>>(W1, W2, W3, W123B);
  if (use_embB) {
    convert_gen<<<dim3(4096), blk, 0, stream>>>(emb, embB);
    gemm_qkv<unsigned short><<<dim3(24, 64), blk, 0, stream>>>(embB, W123B, q, k, vn);
  } else {
    gemm_qkv<float><<<dim3(24, 64), blk, 0, stream>>>(emb, W123B, q, k, vn);
  }
  transpose_v<<<dim3(32, 2, 32), blk, 0, stream>>>(vn, vT);
  flash_attn<<<dim3(512, 1, 1), blk, 0, stream>>>(q, k, vT, oT);
  convert_gen<<<dim3(512), blk, 0, stream>>>(Wo, WoB);
  gemm_out<<<dim3(8, 64), blk, 0, stream>>>(oT, WoB, out);
}

// Round 8
// 362.015 us; speedup vs baseline: 4.3674x; 1.0115x over previous
//
#include <hip/hip_runtime.h>

typedef float f32x4 __attribute__((ext_vector_type(4)));
typedef __bf16 bf16x8 __attribute__((ext_vector_type(8)));

__device__ __forceinline__ unsigned short f2bf(float f) {
  unsigned int u = __float_as_uint(f);
  u = (u + 0x7FFFu + ((u >> 16) & 1u)) >> 16;
  return (unsigned short)u;
}

__device__ __forceinline__ f32x4 mfma16(bf16x8 a, bf16x8 b, f32x4 c) {
  return __builtin_amdgcn_mfma_f32_16x16x32_bf16(a, b, c, 0, 0, 0);
}

__device__ __forceinline__ void load8_bf16(const unsigned short* p, unsigned short* d) {
  *(uint4*)d = *(const uint4*)p;
}
__device__ __forceinline__ void load8_bf16(const float* p, unsigned short* d) {
  float4 a = *(const float4*)p;
  float4 b = *(const float4*)(p + 4);
  __align__(16) unsigned short t[8] = {f2bf(a.x), f2bf(a.y), f2bf(a.z), f2bf(a.w),
                                       f2bf(b.x), f2bf(b.y), f2bf(b.z), f2bf(b.w)};
  *(uint4*)d = *(uint4*)t;
}

// Async global->LDS 16B DMA. LDS dest must be wave-uniform base + lane*16
// (our staging maps are exactly lane-linear per wave).
__device__ __forceinline__ void gload_lds16(const unsigned short* g, unsigned short* l) {
  __builtin_amdgcn_global_load_lds(
      (const __attribute__((address_space(1))) void*)g,
      (__attribute__((address_space(3))) void*)l, 16, 0, 0);
}

// fp32 -> bf16, 8 elems/thread.
__global__ __launch_bounds__(256) void convert_gen(const float* __restrict__ src,
                                                   unsigned short* __restrict__ dst) {
  int idx = (blockIdx.x * 256 + threadIdx.x) * 8;
  __align__(16) unsigned short t[8];
  load8_bf16(src + idx, t);
  *(uint4*)(dst + idx) = *(uint4*)t;
}

// W1|W2|W3 (each 1M fp32) -> contiguous bf16. 1536 blocks.
__global__ __launch_bounds__(256) void convert_w3(const float* __restrict__ W1,
                                                  const float* __restrict__ W2,
                                                  const float* __restrict__ W3,
                                                  unsigned short* __restrict__ dst) {
  int i = blockIdx.x;
  int sel = i >> 9;
  const float* src = (sel == 0) ? W1 : (sel == 1) ? W2 : W3;
  int off = (i & 511) * 2048 + threadIdx.x * 8;
  __align__(16) unsigned short t[8];
  load8_bf16(src + off, t);
  *(uint4*)(dst + sel * 1048576 + off) = *(uint4*)t;
}

// Fused QKV projection, all-bf16, global_load_lds staging, unpadded LDS.
// blockIdx.x in [0,24): sel = x>>3 (0:q,1:k,2:v), nb=(x&7)*128.
__global__ __launch_bounds__(256) void gemm_qkv(const unsigned short* __restrict__ A,
                                                const unsigned short* __restrict__ WB,
                                                unsigned short* __restrict__ q,
                                                unsigned short* __restrict__ k,
                                                unsigned short* __restrict__ v) {
  __shared__ __align__(16) unsigned short As[128][32];  // unpadded: lane-linear staging,
  __shared__ __align__(16) unsigned short Bs[128][32];  // b128 reads granule-uniform
  const int t = threadIdx.x;
  const int lane = t & 63;
  const int wid = t >> 6;
  const int quad = lane >> 4;
  const int l16 = lane & 15;
  const int wm = (wid >> 1) << 6;
  const int wn = (wid & 1) << 6;
  const int sel = blockIdx.x >> 3;
  const int nb = (blockIdx.x & 7) << 7;
  const int mbase = blockIdx.y * 128;
  const unsigned short* Bt = WB + sel * 1048576;
  unsigned short* C = (sel == 0) ? q : (sel == 1) ? k : v;

  f32x4 acc[4][4] = {};

  for (int k0 = 0; k0 < 1024; k0 += 32) {
#pragma unroll
    for (int i = 0; i < 2; ++i) {
      int c = t + (i << 8);
      int row = c >> 2;
      int col = (c & 3) << 3;
      gload_lds16(A + (size_t)(mbase + row) * 1024 + k0 + col, &As[row][col]);
      gload_lds16(Bt + (size_t)(nb + row) * 1024 + k0 + col, &Bs[row][col]);
    }
    __syncthreads();
    bf16x8 af[4], bfr[4];
#pragma unroll
    for (int mt = 0; mt < 4; ++mt)
      af[mt] = *(const bf16x8*)(&As[wm + mt * 16 + l16][quad * 8]);
#pragma unroll
    for (int nt = 0; nt < 4; ++nt)
      bfr[nt] = *(const bf16x8*)(&Bs[wn + nt * 16 + l16][quad * 8]);
#pragma unroll
    for (int mt = 0; mt < 4; ++mt)
#pragma unroll
      for (int nt = 0; nt < 4; ++nt)
        acc[mt][nt] = mfma16(af[mt], bfr[nt], acc[mt][nt]);
    __syncthreads();
  }

  const bool rope = (sel < 2);
#pragma unroll
  for (int mt = 0; mt < 4; ++mt) {
#pragma unroll
    for (int nt = 0; nt < 4; ++nt) {
#pragma unroll
      for (int r = 0; r < 4; ++r) {
        int row_g = mbase + wm + mt * 16 + quad * 4 + r;
        int col_g = nb + wn + nt * 16 + l16;
        float val = acc[mt][nt][r];
        if (rope) {  // interleaved RoPE; partner col = col^1 lives in lane^1
          float other = __shfl_xor(val, 1);
          int s = (((row_g & 2047) << 3) + (col_g >> 7)) & 2047;  // view-seq position
          int d = col_g & 127;
          float invf = __expf(-0.14391156f * (float)(d >> 1));  // ln(1e4)/64
          float ang = (float)s * invf;
          float sv, cv;
          __sincosf(ang, &sv, &cv);
          val = (d & 1) ? (val * cv + other * sv) : (val * cv - other * sv);
        }
        C[(size_t)row_g * 1024 + col_g] = f2bf(val);
      }
    }
  }
}

// Plain per-bh transpose: vT[bh][d][s] = v[bh][s][d].
__global__ __launch_bounds__(256) void transpose_v(const unsigned short* __restrict__ Vn,
                                                   unsigned short* __restrict__ VT) {
  __shared__ __align__(16) unsigned short tile[64][72];
  const int t = threadIdx.x;
  const int s0 = blockIdx.x * 64;
  const int d0 = blockIdx.y * 64;
  const int bh = blockIdx.z;
  const size_t base = (size_t)bh * (2048 * 128);
#pragma unroll
  for (int i = 0; i < 2; ++i) {
    int c = t + (i << 8);
    int sr = c >> 3;
    int dc = (c & 7) << 3;
    *(uint4*)(&tile[sr][dc]) = *(const uint4*)(Vn + base + (size_t)(s0 + sr) * 128 + d0 + dc);
  }
  __syncthreads();
#pragma unroll
  for (int i = 0; i < 2; ++i) {
    int c = t + (i << 8);
    int dr = c >> 3;
    int sc = (c & 7) << 3;
    __align__(16) unsigned short tmp[8];
#pragma unroll
    for (int j = 0; j < 8; ++j) tmp[j] = tile[sc + j][dr];
    *(uint4*)(VT + base + (size_t)(d0 + dr) * 2048 + s0 + sc) = *(uint4*)tmp;
  }
}

// Final projection: A rows remap RowLinear pre-shuffle onto oT[bh][d][s];
// global_load_lds staging; output-permutation fp32 store (LDS transposed, coalesced).
__global__ __launch_bounds__(256) void gemm_out(const unsigned short* __restrict__ OT,
                                                const unsigned short* __restrict__ Bt,
                                                float* __restrict__ C) {
  __shared__ __align__(16) char smem_raw[128 * 68 * 4];  // Ts epilogue needs 34816 B
  auto As = (unsigned short(*)[32])smem_raw;
  auto Bs = (unsigned short(*)[32])(smem_raw + 128 * 32 * 2);
  const int t = threadIdx.x;
  const int lane = t & 63;
  const int wid = t >> 6;
  const int quad = lane >> 4;
  const int l16 = lane & 15;
  const int wm = (wid >> 1) << 6;
  const int wn = (wid & 1) << 6;
  const int mbase = blockIdx.y * 128;
  const int nbase = blockIdx.x * 128;

  f32x4 acc[4][4] = {};

  for (int k0 = 0; k0 < 1024; k0 += 32) {
#pragma unroll
    for (int i = 0; i < 2; ++i) {
      int c = t + (i << 8);
      int row = c >> 2;
      int col = (c & 3) << 3;
      int R = mbase + row;
      int b = R >> 11;
      int ii = R & 2047;
      const unsigned short* src = OT + (size_t)(b * 8 + (ii >> 8)) * (128 * 2048) +
                                  (size_t)((ii >> 1) & 127) * 2048 + ((ii & 1) << 10) +
                                  k0 + col;
      gload_lds16(src, &As[row][col]);
      gload_lds16(Bt + (size_t)(nbase + row) * 1024 + k0 + col, &Bs[row][col]);
    }
    __syncthreads();
    bf16x8 af[4], bfr[4];
#pragma unroll
    for (int mt = 0; mt < 4; ++mt)
      af[mt] = *(const bf16x8*)(&As[wm + mt * 16 + l16][quad * 8]);
#pragma unroll
    for (int nt = 0; nt < 4; ++nt)
      bfr[nt] = *(const bf16x8*)(&Bs[wn + nt * 16 + l16][quad * 8]);
#pragma unroll
    for (int mt = 0; mt < 4; ++mt)
#pragma unroll
      for (int nt = 0; nt < 4; ++nt)
        acc[mt][nt] = mfma16(af[mt], bfr[nt], acc[mt][nt]);
    __syncthreads();
  }

  // out[b][s2][e2], s2 = (row&1)*1024 + col, e2 = (row&2047)>>1.
  float(*Ts)[68] = (float(*)[68])smem_raw;
  const int b = mbase >> 11;
  const int ebase = (mbase & 2047) >> 1;
#pragma unroll
  for (int p = 0; p < 2; ++p) {
    __syncthreads();
#pragma unroll
    for (int mt = 0; mt < 4; ++mt)
#pragma unroll
      for (int nt = 0; nt < 4; ++nt)
#pragma unroll
        for (int rr = p; rr < 4; rr += 2) {
          int col_local = wn + nt * 16 + l16;
          int row_local = wm + mt * 16 + quad * 4 + rr;
          Ts[col_local][row_local >> 1] = acc[mt][nt][rr];
        }
    __syncthreads();
    int srow = t >> 1;
    int e0 = (t & 1) << 5;
    float* dst = C + (size_t)b * 2097152 +
                 (size_t)(p * 1024 + nbase + srow) * 1024 + ebase + e0;
#pragma unroll
    for (int j = 0; j < 8; ++j)
      ((float4*)dst)[j] = *(const float4*)&Ts[srow][e0 + j * 4];
  }
}

// Flash attention [BH=32, S=2048, D=128]; BQ=128 (4 waves x 32 rows), BKV=64.
// V pre-transposed (vT[bh][d][s]); O written transposed (oT[bh][d][s]).
// Row-sum l via ones-fragment MFMA.
__global__ __launch_bounds__(256, 2) void flash_attn(const unsigned short* __restrict__ Q,
                                                     const unsigned short* __restrict__ Kg,
                                                     const unsigned short* __restrict__ VTg,
                                                     unsigned short* __restrict__ OT) {
  __shared__ __align__(16) char sm[54272];
  auto Ks = (unsigned short(*)[136])sm;
  auto Vt = (unsigned short(*)[72])(sm + 17408);
  auto Ps = (unsigned short(*)[32][72])(sm + 35840);
  const int t = threadIdx.x;
  const int lane = t & 63;
  const int wid = t >> 6;
  const int quad = lane >> 4;
  const int l16 = lane & 15;
  const int i = blockIdx.x;                 // [0,512); XCD-aware swizzle
  const int bh = (i & 7) + ((i >> 3) & 3) * 8;
  const int qbase = (i >> 5) << 7;
  const size_t base = (size_t)bh * (2048 * 128);
  const float scale = 0.3535533905932738f;  // 1/sqrt(H=8)

  bf16x8 ones8;
#pragma unroll
  for (int j = 0; j < 8; ++j) ones8[j] = (__bf16)1.0f;

  bf16x8 qf[2][4];
#pragma unroll
  for (int mt = 0; mt < 2; ++mt) {
    int row = qbase + wid * 32 + mt * 16 + l16;
#pragma unroll
    for (int ks = 0; ks < 4; ++ks)
      qf[mt][ks] = *(const bf16x8*)(Q + base + (size_t)row * 128 + ks * 32 + quad * 8);
  }

  f32x4 accO[2][8] = {};
  f32x4 accL[2] = {};
  float mst[2][4];
#pragma unroll
  for (int mt = 0; mt < 2; ++mt)
#pragma unroll
    for (int r = 0; r < 4; ++r) mst[mt][r] = -__builtin_inff();

  for (int kv0 = 0; kv0 < 2048; kv0 += 64) {
#pragma unroll
    for (int i2 = 0; i2 < 4; ++i2) {
      int c = t + (i2 << 8);
      int row = c >> 4;
      int col = (c & 15) << 3;
      *(uint4*)(&Ks[row][col]) = *(const uint4*)(Kg + base + (size_t)(kv0 + row) * 128 + col);
    }
#pragma unroll
    for (int i2 = 0; i2 < 4; ++i2) {
      int c = t + (i2 << 8);
      int row = c >> 3;
      int col = (c & 7) << 3;
      *(uint4*)(&Vt[row][col]) =
          *(const uint4*)(VTg + base + (size_t)row * 2048 + kv0 + col);
    }
    __syncthreads();

    f32x4 accS[2][4];
#pragma unroll
    for (int nt = 0; nt < 4; ++nt) {
      bf16x8 kf[4];
#pragma unroll
      for (int ks = 0; ks < 4; ++ks)
        kf[ks] = *(const bf16x8*)(&Ks[nt * 16 + l16][ks * 32 + quad * 8]);
#pragma unroll
      for (int mt = 0; mt < 2; ++mt) {
        f32x4 a = {0.f, 0.f, 0.f, 0.f};
#pragma unroll
        for (int ks = 0; ks < 4; ++ks)
          a = mfma16(qf[mt][ks], kf[ks], a);
        accS[mt][nt] = a;
      }
    }

#pragma unroll
    for (int mt = 0; mt < 2; ++mt) {
#pragma unroll
      for (int r = 0; r < 4; ++r) {
        float mx = fmaxf(fmaxf(accS[mt][0][r], accS[mt][1][r]),
                         fmaxf(accS[mt][2][r], accS[mt][3][r]));
#pragma unroll
        for (int off = 1; off < 16; off <<= 1) mx = fmaxf(mx, __shfl_xor(mx, off));
        float mnew = fmaxf(mst[mt][r], mx);
        float alpha = __expf((mst[mt][r] - mnew) * scale);
        float negms = -mnew * scale;
#pragma unroll
        for (int nt = 0; nt < 4; ++nt)
          accS[mt][nt][r] = __expf(fmaf(accS[mt][nt][r], scale, negms));
        mst[mt][r] = mnew;
        accL[mt][r] *= alpha;
#pragma unroll
        for (int dt = 0; dt < 8; ++dt) accO[mt][dt][r] *= alpha;
      }
    }

#pragma unroll
    for (int mt = 0; mt < 2; ++mt)
#pragma unroll
      for (int nt = 0; nt < 4; ++nt)
#pragma unroll
        for (int r = 0; r < 4; ++r)
          Ps[wid][mt * 16 + quad * 4 + r][nt * 16 + l16] = f2bf(accS[mt][nt][r]);

    bf16x8 pf[2][2];
#pragma unroll
    for (int mt = 0; mt < 2; ++mt)
#pragma unroll
      for (int ks = 0; ks < 2; ++ks)
        pf[mt][ks] = *(const bf16x8*)(&Ps[wid][mt * 16 + l16][ks * 32 + quad * 8]);

#pragma unroll
    for (int mt = 0; mt < 2; ++mt)
#pragma unroll
      for (int ks = 0; ks < 2; ++ks)
        accL[mt] = mfma16(pf[mt][ks], ones8, accL[mt]);

#pragma unroll
    for (int dt = 0; dt < 8; ++dt) {
      bf16x8 vf[2];
#pragma unroll
      for (int ks = 0; ks < 2; ++ks)
        vf[ks] = *(const bf16x8*)(&Vt[dt * 16 + l16][ks * 32 + quad * 8]);
#pragma unroll
      for (int mt = 0; mt < 2; ++mt)
#pragma unroll
        for (int ks = 0; ks < 2; ++ks)
          accO[mt][dt] = mfma16(pf[mt][ks], vf[ks], accO[mt][dt]);
    }
    __syncthreads();
  }

  auto To = (unsigned short(*)[136])sm;
#pragma unroll
  for (int mt = 0; mt < 2; ++mt) {
#pragma unroll
    for (int r = 0; r < 4; ++r) {
      float inv = 1.f / accL[mt][r];
      int srow = wid * 32 + mt * 16 + quad * 4 + r;
#pragma unroll
      for (int dt = 0; dt < 8; ++dt)
        To[dt * 16 + l16][srow] = f2bf(accO[mt][dt][r] * inv);
    }
  }
  __syncthreads();
  int dr = t >> 1;
  int off = (t & 1) << 6;
  unsigned short* dst = OT + base + (size_t)dr * 2048 + qbase + off;
#pragma unroll
  for (int j = 0; j < 8; ++j)
    ((uint4*)dst)[j] = *(const uint4*)&To[dr][off + j * 8];
}

extern "C" void kernel_launch(void* const* d_in, const int* in_sizes, int n_in,
                              void* d_out, int out_size, void* d_ws, size_t ws_size,
                              hipStream_t stream) {
  const float* emb = (const float*)d_in[0];
  const float* W1  = (const float*)d_in[1];
  const float* W2  = (const float*)d_in[2];
  const float* W3  = (const float*)d_in[3];
  const float* Wo  = (const float*)d_in[4];
  float* out = (float*)d_out;

  const size_t NELEM = (size_t)8 * 1024 * 1024;  // bf16 elems per [B*S, P] buffer
  unsigned short* q     = (unsigned short*)d_ws;   // [0,16) MB
  unsigned short* k     = q + NELEM;               // [16,32)
  unsigned short* vn    = k + NELEM;               // [32,48); later oT
  unsigned short* X     = vn + NELEM;              // [48,64): W123B -> vT -> WoB
  unsigned short* oT    = vn;
  unsigned short* vT    = X;
  unsigned short* W123B = X;                       // 6 MB, dead before vT written
  unsigned short* WoB   = X;                       // 2 MB, written after flash
  unsigned short* embB  = (unsigned short*)d_out;  // 16 MB bf16 scratch in the 32 MB
                                                   // fp32 out buffer; overwritten by gemm_out

  dim3 blk(256, 1, 1);
  convert_w3<<<dim3(1536), blk, 0, stream>>>(W1, W2, W3, W123B);
  convert_gen<<<dim3(4096), blk, 0, stream>>>(emb, embB);
  gemm_qkv<<<dim3(24, 64), blk, 0, stream>>>(embB, W123B, q, k, vn);
  transpose_v<<<dim3(32, 2, 32), blk, 0, stream>>>(vn, vT);
  flash_attn<<<dim3(512, 1, 1), blk, 0, stream>>>(q, k, vT, oT);
  convert_gen<<<dim3(512), blk, 0, stream>>>(Wo, WoB);
  gemm_out<<<dim3(8, 64), blk, 0, stream>>>(oT, WoB, out);
}